// Round 8
// baseline (7669.333 us; speedup 1.0000x reference)
//
#include <hip/hip_runtime.h>

typedef unsigned short u16;
typedef unsigned int   u32;
typedef __attribute__((ext_vector_type(8))) short short8;
typedef __attribute__((ext_vector_type(4))) float f32x4;

#define DEV static __device__ __forceinline__

DEV float bf2f(u16 u) { return __uint_as_float(((u32)u) << 16); }
DEV u16 f2bf(float f) {
  u32 u = __float_as_uint(f);
  return (u16)((u + 0x7fffu + ((u >> 16) & 1u)) >> 16);
}

#define GLD16(gp, lp) __builtin_amdgcn_global_load_lds( \
    (__attribute__((address_space(1))) u32*)(gp),       \
    (__attribute__((address_space(3))) u32*)(lp), 16, 0, 0)

#define SBAR()  asm volatile("s_barrier" ::: "memory")
#define LGKM0() asm volatile("s_waitcnt lgkmcnt(0)" ::: "memory")

// ---------------------------------------------------------------------------
// Grouped GEMM: 256x256 tile, BK=32, 8 waves (2M x 4N), 64KB LDS ->
// 2 blocks/CU (4 waves/SIMD). Per 32-K tile, 2 phases:
//  ph0 {read A(m0-3)+B(n0-3) | stage A(t+1) -> bar,lgkm0 -> 16 MFMA -> bar}
//  ph1 {read A(m4-7) | stage B(t+2) -> bar,lgkm0 -> 16 MFMA(B reg-reuse)
//       -> vmcnt(2) -> bar}
// Counted vmcnt: B(t+2) stays in flight across the tile boundary; drain only
// at the K-tail. T1 XCD swizzle, T2 granule-XOR (perm = g ^ ((row^(row>>2))&3),
// 2-way bank alias = free), T5 setprio, n-innermost C store.
// M%256==0, N%256==0, K%32==0.
// ---------------------------------------------------------------------------
__global__ __launch_bounds__(512, 4) void gemm_bf16(
    const u16* __restrict__ A, const u16* __restrict__ Bw, u16* __restrict__ C,
    const float* __restrict__ bias, int M, int N, int K,
    long sAz, long sBz, long sCz, long sBiasZ, int relu)
{
  __shared__ __align__(16) u16 Asm[2][2][4096];   // [dbuf][half][128*32]
  __shared__ __align__(16) u16 Bsm[2][2][4096];

  // T1: bijective XCD swizzle over the flattened grid (x-fastest decompose)
  int gx = (int)gridDim.x, gy = (int)gridDim.y;
  int nwg = gx * gy * (int)gridDim.z;
  int orig = (int)blockIdx.x + gx * ((int)blockIdx.y + gy * (int)blockIdx.z);
  int qq = nwg >> 3, rr_ = nwg & 7;
  int xcd = orig & 7, pos = orig >> 3;
  int lg_id = (xcd < rr_) ? (xcd * (qq + 1) + pos) : (rr_ * (qq + 1) + (xcd - rr_) * qq + pos);
  int bz = lg_id / (gx * gy);
  int rem = lg_id - bz * (gx * gy);
  int by = rem / gx, bx = rem - by * gx;

  A += (size_t)bz * sAz; Bw += (size_t)bz * sBz; C += (size_t)bz * sCz; bias += (size_t)bz * sBiasZ;
  int tileM = bx * 256, tileN = by * 256;
  int tid = threadIdx.x, wave = tid >> 6, lane = tid & 63;
  int lr = lane & 15, lgp = lane >> 4;
  int wm = (wave >> 2) * 128;          // wave's M offset
  int wn = (wave & 3) * 64;            // wave's N offset
  int ah = wave >> 2;                  // A-half slot this wave reads
  int bh = (wave & 3) >> 1;            // B-half slot this wave reads
  int bnb = ((wave & 3) & 1) * 64;     // local n-row base within B-half

  const int NT = K >> 5;
  const u16* Abase = A + (size_t)tileM * K;
  const u16* Bbase = Bw + (size_t)tileN * K;

  // stage one 128x32 half-tile (8KB): 512 threads x 1 GLD16; granule-XOR
  // pre-swizzled global source, linear LDS dest.
  int srow = tid >> 2, sg = tid & 3;
  int ssw = (sg ^ ((srow ^ (srow >> 2)) & 3)) * 8;
  auto SA = [&](int b, int h, int t) {
    const u16* src = Abase + (size_t)h * 128 * K + t * 32;
    GLD16(src + (size_t)srow * K + ssw, Asm[b][h] + (size_t)tid * 8);
  };
  auto SB = [&](int b, int h, int t) {
    const u16* src = Bbase + (size_t)h * 128 * K + t * 32;
    GLD16(src + (size_t)srow * K + ssw, Bsm[b][h] + (size_t)tid * 8);
  };

  f32x4 acc[8][4] = {};

  // prologue: tile0 all 4 halves -> buf0; tile1 B-halves -> buf1
  SA(0, 0, 0); SA(0, 1, 0); SB(0, 0, 0); SB(0, 1, 0);
  if (NT > 1) {
    SB(1, 0, 1); SB(1, 1, 1);
    asm volatile("s_waitcnt vmcnt(2)" ::: "memory");
  } else {
    asm volatile("s_waitcnt vmcnt(0)" ::: "memory");
  }
  SBAR();

  for (int t = 0; t < NT; ++t) {
    int cur = t & 1;
    const u16* Aslot = Asm[cur][ah];
    const u16* Bslot = Bsm[cur][bh];
    short8 afr[4], bfr[4];

    // ---- phase 0: read A(m0-3) + B(n0-3); stage A halves of tile t+1
    #pragma unroll
    for (int mm = 0; mm < 4; ++mm) {
      int rw = mm * 16 + lr;
      afr[mm] = *(const short8*)(Aslot + rw * 32 + ((lgp ^ ((rw ^ (rw >> 2)) & 3)) * 8));
    }
    #pragma unroll
    for (int nn = 0; nn < 4; ++nn) {
      int rw = bnb + nn * 16 + lr;
      bfr[nn] = *(const short8*)(Bslot + rw * 32 + ((lgp ^ ((rw ^ (rw >> 2)) & 3)) * 8));
    }
    if (t + 1 < NT) { SA(cur ^ 1, 0, t + 1); SA(cur ^ 1, 1, t + 1); }
    SBAR(); LGKM0();
    __builtin_amdgcn_s_setprio(1);
    #pragma unroll
    for (int mm = 0; mm < 4; ++mm)
      #pragma unroll
      for (int nn = 0; nn < 4; ++nn)
        acc[mm][nn] = __builtin_amdgcn_mfma_f32_16x16x32_bf16(
            afr[mm], bfr[nn], acc[mm][nn], 0, 0, 0);
    __builtin_amdgcn_s_setprio(0);
    SBAR();

    // ---- phase 1: read A(m4-7); stage B halves of tile t+2
    #pragma unroll
    for (int mm = 0; mm < 4; ++mm) {
      int rw = (mm + 4) * 16 + lr;
      afr[mm] = *(const short8*)(Aslot + rw * 32 + ((lgp ^ ((rw ^ (rw >> 2)) & 3)) * 8));
    }
    if (t + 2 < NT) { SB(cur, 0, t + 2); SB(cur, 1, t + 2); }
    SBAR(); LGKM0();
    __builtin_amdgcn_s_setprio(1);
    #pragma unroll
    for (int mm = 0; mm < 4; ++mm)
      #pragma unroll
      for (int nn = 0; nn < 4; ++nn)
        acc[mm + 4][nn] = __builtin_amdgcn_mfma_f32_16x16x32_bf16(
            afr[mm], bfr[nn], acc[mm + 4][nn], 0, 0, 0);
    __builtin_amdgcn_s_setprio(0);
    if (t + 2 < NT) asm volatile("s_waitcnt vmcnt(2)" ::: "memory");
    else            asm volatile("s_waitcnt vmcnt(0)" ::: "memory");
    SBAR();
  }

  // epilogue: n-innermost store order (adjacent stores complete each C-line)
  float bb[4];
  #pragma unroll
  for (int n = 0; n < 4; ++n) bb[n] = bias[tileN + wn + n * 16 + lr];
  #pragma unroll
  for (int m = 0; m < 8; ++m) {
    #pragma unroll
    for (int rr = 0; rr < 4; ++rr) {
      int mrow = tileM + wm + m * 16 + lgp * 4 + rr;
      u16* crow = C + (size_t)mrow * N + tileN + wn + lr;
      #pragma unroll
      for (int n = 0; n < 4; ++n) {
        float v = acc[m][n][rr] + bb[n];
        if (relu) v = fmaxf(v, 0.f);
        crow[n * 16] = f2bf(v);
      }
    }
  }
}

// ---------------------------------------------------------------------------
// fp32 -> bf16 weight slice conversion
// ---------------------------------------------------------------------------
__global__ void cvt_w_kernel(const float* __restrict__ src, u16* __restrict__ dst,
                             long n_per_f, long f_stride, long total4)
{
  long i = (long)blockIdx.x * blockDim.x + threadIdx.x;
  long step = (long)gridDim.x * blockDim.x;
  for (; i < total4; i += step) {
    long e = i * 4;
    long f = e / n_per_f; long r = e - f * n_per_f;
    float4 v = *(const float4*)(src + f * f_stride + r);
    *(ushort4*)(dst + e) = make_ushort4(f2bf(v.x), f2bf(v.y), f2bf(v.z), f2bf(v.w));
  }
}

// ---------------------------------------------------------------------------
// Embeddings (unchanged)
// ---------------------------------------------------------------------------
__global__ __launch_bounds__(128) void embed_enc_k(
    const float* __restrict__ x, const float* __restrict__ mark,
    const float* __restrict__ w_in, const float* __restrict__ b_in,
    u16* __restrict__ hb)
{
  int row = blockIdx.x;
  int f = row / 5376; int rem = row - f * 5376; int b = rem / 336; int s = rem - b * 336;
  int bsix = b * 336 + s;
  float v0 = x[(size_t)bsix * 7 + f];
  float m0 = mark[(size_t)bsix * 4 + 0], m1 = mark[(size_t)bsix * 4 + 1];
  float m2 = mark[(size_t)bsix * 4 + 2], m3 = mark[(size_t)bsix * 4 + 3];
  int d0 = threadIdx.x * 4;
  u16 ob[4];
  #pragma unroll
  for (int c = 0; c < 4; c++) {
    int d = d0 + c;
    const float* w = w_in + d * 5;
    float val = w[0] * v0 + w[1] * m0 + w[2] * m1 + w[3] * m2 + w[4] * m3 + b_in[d];
    int i = d >> 1;
    float dv = expf((float)i * -0.0359778920778f);
    float arg = (float)s * dv;
    val += (d & 1) ? cosf(arg) : sinf(arg);
    ob[c] = f2bf(val);
  }
  *(ushort4*)(hb + (size_t)row * 512 + d0) = make_ushort4(ob[0], ob[1], ob[2], ob[3]);
}

__global__ __launch_bounds__(128) void embed_dec_k(
    const float* __restrict__ ymark, const float* __restrict__ w_co,
    const float* __restrict__ b_co, u16* __restrict__ tb)
{
  int row = blockIdx.x;
  int f = row / 1536; int rem = row - f * 1536; int b = rem / 96; int pp = rem - b * 96;
  int bp = b * 96 + pp;
  float m0 = ymark[(size_t)bp * 4 + 0], m1 = ymark[(size_t)bp * 4 + 1];
  float m2 = ymark[(size_t)bp * 4 + 2], m3 = ymark[(size_t)bp * 4 + 3];
  int d0 = threadIdx.x * 4;
  u16 ob[4];
  #pragma unroll
  for (int c = 0; c < 4; c++) {
    int d = d0 + c;
    const float* w = w_co + d * 4;
    float val = w[0] * m0 + w[1] * m1 + w[2] * m2 + w[3] * m3 + b_co[d];
    int i = d >> 1;
    float dv = expf((float)i * -0.0359778920778f);
    float arg = (float)pp * dv;
    val += (d & 1) ? cosf(arg) : sinf(arg);
    ob[c] = f2bf(val);
  }
  *(ushort4*)(tb + (size_t)row * 512 + d0) = make_ushort4(ob[0], ob[1], ob[2], ob[3]);
}

// ---------------------------------------------------------------------------
// MFMA attention (unchanged from round 6/7 — passing)
// ---------------------------------------------------------------------------
template<int LK, int CHUNK, int NQI>
__global__ __launch_bounds__(256) void attn_mfma(
    const u16* __restrict__ q, const u16* __restrict__ k, const u16* __restrict__ v,
    u16* __restrict__ out, int Lq, int qstride, int kvstride, int causal, int qspan)
{
  constexpr int NCH = LK / CHUNK;
  constexpr int NKT = CHUNK / 16;
  constexpr int NKS = (CHUNK + 31) / 32;
  constexpr int KPAD = NKS * 32;
  constexpr int VSTR = KPAD + 8;
  constexpr int NGRP = CHUNK * 8 / 64;

  __shared__ __align__(16) u16 KsS[CHUNK * 64];
  __shared__ __align__(16) u16 VtS[64 * VSTR];
  __shared__ __align__(16) u16 PWS[4][16 * VSTR];

  int hh = blockIdx.x, fb = blockIdx.y;
  int tid = threadIdx.x, wave = tid >> 6, lane = tid & 63;
  int lr = lane & 15, lg = lane >> 4;

  const int nqt = Lq / 16;
  const int qlo = (int)blockIdx.z * qspan;
  const int qhi = (qlo + qspan < nqt) ? (qlo + qspan) : nqt;

  const u16* qp = q + (size_t)fb * Lq * qstride + hh * 64;
  const u16* kp = k + (size_t)fb * LK * kvstride + hh * 64;
  const u16* vp = v + (size_t)fb * LK * kvstride + hh * 64;

  if constexpr (KPAD > CHUNK) {
    constexpr int TW = KPAD - CHUNK;
    for (int i = tid; i < 64 * TW; i += 256)
      VtS[(i / TW) * VSTR + CHUNK + (i % TW)] = 0;
    u16* PW = PWS[wave];
    for (int i = lane; i < 16 * TW; i += 64)
      PW[(i / TW) * VSTR + CHUNK + (i % TW)] = 0;
  }

  f32x4 oacc[NQI][4] = {};
  f32x4 lsum[NQI] = {};
  u16* PW = PWS[wave];

  for (int c = 0; c < NCH; ++c) {
    __syncthreads();

    const u16* kcp = kp + (size_t)c * CHUNK * kvstride;
    for (int grp = wave; grp < NGRP; grp += 4) {
      int gi = grp * 64 + lane;
      int row = gi >> 3, g = gi & 7;
      GLD16(kcp + (size_t)row * kvstride + ((g ^ (row & 7)) * 8), KsS + (size_t)gi * 8);
    }
    const u16* vcp = vp + (size_t)c * CHUNK * kvstride;
    for (int idx = tid; idx < CHUNK * 8; idx += 256) {
      int kk = idx >> 3, dg = idx & 7;
      uint4 pv = *(const uint4*)(vcp + (size_t)kk * kvstride + dg * 8);
      u16* col = VtS + (size_t)(dg * 8) * VSTR + kk;
      col[0 * VSTR] = (u16)pv.x; col[1 * VSTR] = (u16)(pv.x >> 16);
      col[2 * VSTR] = (u16)pv.y; col[3 * VSTR] = (u16)(pv.y >> 16);
      col[4 * VSTR] = (u16)pv.z; col[5 * VSTR] = (u16)(pv.z >> 16);
      col[6 * VSTR] = (u16)pv.w; col[7 * VSTR] = (u16)(pv.w >> 16);
    }
    __syncthreads();

    #pragma unroll
    for (int qi = 0; qi < NQI; ++qi) {
      int qt = qlo + wave + qi * 4;
      if (qt < qhi) {
        const u16* qrow = qp + (size_t)(qt * 16 + lr) * qstride + lg * 8;
        short8 qf0 = *(const short8*)(qrow);
        short8 qf1 = *(const short8*)(qrow + 32);

        f32x4 sacc[NKT];
        #pragma unroll
        for (int t = 0; t < NKT; t++) {
          int row = t * 16 + lr;
          const u16* kb = KsS + row * 64;
          short8 kf0 = *(const short8*)(kb + ((lg ^ (row & 7)) * 8));
          short8 kf1 = *(const short8*)(kb + (((lg + 4) ^ (row & 7)) * 8));
          f32x4 s = {0.f, 0.f, 0.f, 0.f};
          s = __builtin_amdgcn_mfma_f32_16x16x32_bf16(qf0, kf0, s, 0, 0, 0);
          s = __builtin_amdgcn_mfma_f32_16x16x32_bf16(qf1, kf1, s, 0, 0, 0);
          sacc[t] = s;
        }

        #pragma unroll
        for (int t = 0; t < NKT; t++) {
          int kg = c * CHUNK + t * 16 + lr;
          #pragma unroll
          for (int r = 0; r < 4; r++) {
            int qg = qt * 16 + lg * 4 + r;
            float p = (causal && kg > qg) ? 0.f : __expf(sacc[t][r] * 0.125f);
            sacc[t][r] = p;
            lsum[qi][r] += p;
          }
          u16* pw = PW + (size_t)(lg * 4) * VSTR + t * 16 + lr;
          pw[0 * VSTR] = f2bf(sacc[t][0]);
          pw[1 * VSTR] = f2bf(sacc[t][1]);
          pw[2 * VSTR] = f2bf(sacc[t][2]);
          pw[3 * VSTR] = f2bf(sacc[t][3]);
        }

        #pragma unroll
        for (int s = 0; s < NKS; s++) {
          short8 pf = *(const short8*)(PW + (size_t)lr * VSTR + s * 32 + lg * 8);
          #pragma unroll
          for (int j = 0; j < 4; j++) {
            short8 vf = *(const short8*)(VtS + (size_t)(j * 16 + lr) * VSTR + s * 32 + lg * 8);
            oacc[qi][j] = __builtin_amdgcn_mfma_f32_16x16x32_bf16(pf, vf, oacc[qi][j], 0, 0, 0);
          }
        }
      }
    }
  }

  #pragma unroll
  for (int qi = 0; qi < NQI; ++qi) {
    int qt = qlo + wave + qi * 4;
    if (qt < qhi) {
      float l0 = lsum[qi][0], l1 = lsum[qi][1], l2 = lsum[qi][2], l3 = lsum[qi][3];
      #pragma unroll
      for (int m = 1; m < 16; m <<= 1) {
        l0 += __shfl_xor(l0, m);
        l1 += __shfl_xor(l1, m);
        l2 += __shfl_xor(l2, m);
        l3 += __shfl_xor(l3, m);
      }
      float inv[4] = {1.f / l0, 1.f / l1, 1.f / l2, 1.f / l3};
      #pragma unroll
      for (int r = 0; r < 4; r++) {
        size_t orow = (size_t)fb * Lq + qt * 16 + lg * 4 + r;
        u16* ob = out + orow * 512 + hh * 64 + lr;
        #pragma unroll
        for (int j = 0; j < 4; j++)
          ob[j * 16] = f2bf(oacc[qi][j][r] * inv[r]);
      }
    }
  }
}

// ---------------------------------------------------------------------------
// Residual add + LayerNorm (unchanged)
// ---------------------------------------------------------------------------
__global__ __launch_bounds__(128) void ln_kernel(
    u16* __restrict__ h, const u16* __restrict__ delta,
    const float* __restrict__ gamma, const float* __restrict__ beta,
    int rows_per_f, long gstride)
{
  __shared__ float red[2];
  int row = blockIdx.x;
  int f = row / rows_per_f;
  const float* g = gamma + (size_t)f * gstride;
  const float* be = beta + (size_t)f * gstride;
  int d0 = threadIdx.x * 4;
  size_t p = (size_t)row * 512 + d0;
  ushort4 hv = *(const ushort4*)(h + p);
  ushort4 dv = *(const ushort4*)(delta + p);
  float x0 = bf2f(hv.x) + bf2f(dv.x), x1 = bf2f(hv.y) + bf2f(dv.y);
  float x2 = bf2f(hv.z) + bf2f(dv.z), x3 = bf2f(hv.w) + bf2f(dv.w);
  float ssum = x0 + x1 + x2 + x3;
  #pragma unroll
  for (int m = 1; m < 64; m <<= 1) ssum += __shfl_xor(ssum, m);
  if ((threadIdx.x & 63) == 0) red[threadIdx.x >> 6] = ssum;
  __syncthreads();
  float mean = (red[0] + red[1]) * (1.f / 512.f);
  __syncthreads();
  float c0 = x0 - mean, c1 = x1 - mean, c2 = x2 - mean, c3 = x3 - mean;
  float sq = c0 * c0 + c1 * c1 + c2 * c2 + c3 * c3;
  #pragma unroll
  for (int m = 1; m < 64; m <<= 1) sq += __shfl_xor(sq, m);
  if ((threadIdx.x & 63) == 0) red[threadIdx.x >> 6] = sq;
  __syncthreads();
  float var = (red[0] + red[1]) * (1.f / 512.f);
  float rstd = rsqrtf(var + 1e-5f);
  float y0 = c0 * rstd * g[d0 + 0] + be[d0 + 0];
  float y1 = c1 * rstd * g[d0 + 1] + be[d0 + 1];
  float y2 = c2 * rstd * g[d0 + 2] + be[d0 + 2];
  float y3 = c3 * rstd * g[d0 + 3] + be[d0 + 3];
  *(ushort4*)(h + p) = make_ushort4(f2bf(y0), f2bf(y1), f2bf(y2), f2bf(y3));
}

// ---------------------------------------------------------------------------
// mem projection (unchanged)
// ---------------------------------------------------------------------------
__global__ __launch_bounds__(256) void mem_kernel(
    const u16* __restrict__ h, const float* __restrict__ elw,
    const float* __restrict__ elb, u16* __restrict__ memb)
{
  int fb = blockIdx.x; int f = fb >> 4;
  int pc = blockIdx.y;
  int d0 = threadIdx.x * 2;
  const u16* hbase = h + (size_t)fb * 336 * 512;
  const float* wbase = elw + (size_t)f * 96 * 336 + (size_t)pc * 16 * 336;
  float a0[16], a1[16];
  #pragma unroll
  for (int pp = 0; pp < 16; pp++) { a0[pp] = 0.f; a1[pp] = 0.f; }
  for (int s = 0; s < 336; s++) {
    ushort2 h2 = *(const ushort2*)(hbase + (size_t)s * 512 + d0);
    float hx = bf2f(h2.x), hy = bf2f(h2.y);
    #pragma unroll
    for (int pp = 0; pp < 16; pp++) {
      float w = wbase[pp * 336 + s];
      a0[pp] += w * hx; a1[pp] += w * hy;
    }
  }
  #pragma unroll
  for (int pp = 0; pp < 16; pp++) {
    int pidx = pc * 16 + pp;
    size_t row = (size_t)fb * 96 + pidx;
    float e = elb[f * 96 + pidx];
    *(ushort2*)(memb + row * 512 + d0) = make_ushort2(f2bf(a0[pp] + e), f2bf(a1[pp] + e));
  }
}

// ---------------------------------------------------------------------------
// Output head (unchanged)
// ---------------------------------------------------------------------------
__global__ __launch_bounds__(64) void head_kernel(
    const u16* __restrict__ td, const float* __restrict__ wcp, const float* __restrict__ bcp,
    const float* __restrict__ wsp, const float* __restrict__ bsp,
    float* __restrict__ cb, float* __restrict__ sg, int f0)
{
  int rl = blockIdx.x, lane = threadIdx.x;
  size_t row = (size_t)f0 * 1536 + rl;
  const u16* x = td + (size_t)rl * 512;
  float xr[8];
  #pragma unroll
  for (int j = 0; j < 8; j++) xr[j] = bf2f(x[lane + 64 * j]);
  #pragma unroll
  for (int o = 0; o < 16; o++) {
    const float* w = wcp + o * 512;
    float p = 0.f;
    #pragma unroll
    for (int j = 0; j < 8; j++) p += xr[j] * w[lane + 64 * j];
    #pragma unroll
    for (int m = 1; m < 64; m <<= 1) p += __shfl_xor(p, m);
    if (lane == 0) {
      float cv = (p + bcp[o]) / 6.0f + 0.5f;
      cb[row * 16 + o] = fminf(fmaxf(cv, 0.f), 1.f);
    }
  }
  float p = 0.f;
  #pragma unroll
  for (int j = 0; j < 8; j++) p += xr[j] * wsp[lane + 64 * j];
  #pragma unroll
  for (int m = 1; m < 64; m <<= 1) p += __shfl_xor(p, m);
  if (lane == 0) {
    float zv = p + bsp[0];
    sg[row] = (zv > 20.f) ? zv : log1pf(expf(zv));
  }
}

// ---------------------------------------------------------------------------
// TAO scan (unchanged)
// ---------------------------------------------------------------------------
__global__ __launch_bounds__(256) void scan_kernel(
    const float* __restrict__ cbuf, const float* __restrict__ sgb, float* __restrict__ outp)
{
  int f = blockIdx.x;
  int b = threadIdx.x >> 4;
  int s = threadIdx.x & 15;
  size_t rbase = ((size_t)f * 16 + b) * 96;
  float a = cbuf[rbase * 16 + s];
  for (int p = 0; p < 96; ++p) {
    float cd = cbuf[(rbase + p) * 16 + s];
    float sd = sgb[rbase + p];
    float xs = (s >= 1 && s <= 14) ? a : 0.f;
    #pragma unroll
    for (int m = 1; m < 16; m <<= 1) xs += __shfl_xor(xs, m);
    float up = __shfl_up(a, 1, 16);
    float an = (s == 0) ? (a + cd) : ((s == 1) ? (cd - xs) : (up + cd));
    a = an;
    float y01 = __shfl(a, 0, 16) + __shfl(a, 1, 16) + sd;
    if (s == 0) outp[((size_t)b * 96 + p) * 7 + f] = y01;
  }
}

__global__ void diag_kernel(float* __restrict__ out, float v, int n)
{
  int i = blockIdx.x * 256 + threadIdx.x;
  if (i < n) out[i] = v;
}

// ---------------------------------------------------------------------------
extern "C" void kernel_launch(void* const* d_in, const int* in_sizes, int n_in,
                              void* d_out, int out_size, void* d_ws, size_t ws_size,
                              hipStream_t stream)
{
  (void)in_sizes; (void)n_in;
  const float* batch_x      = (const float*)d_in[0];
  const float* batch_x_mark = (const float*)d_in[1];
  const float* batch_y_mark = (const float*)d_in[3];
  const float* w_in = (const float*)d_in[4];
  const float* b_in = (const float*)d_in[5];
  const float* w_co = (const float*)d_in[6];
  const float* b_co = (const float*)d_in[7];
  const float* eqw  = (const float*)d_in[8];
  const float* eqb  = (const float*)d_in[9];
  const float* eow  = (const float*)d_in[10];
  const float* eob  = (const float*)d_in[11];
  const float* el1w = (const float*)d_in[12];
  const float* el1b = (const float*)d_in[13];
  const float* el2w = (const float*)d_in[14];
  const float* el2b = (const float*)d_in[15];
  const float* ef1w = (const float*)d_in[16];
  const float* ef1b = (const float*)d_in[17];
  const float* ef2w = (const float*)d_in[18];
  const float* ef2b = (const float*)d_in[19];
  const float* elw  = (const float*)d_in[20];
  const float* elb  = (const float*)d_in[21];
  const float* dsqw = (const float*)d_in[22];
  const float* dsqb = (const float*)d_in[23];
  const float* dsow = (const float*)d_in[24];
  const float* dsob = (const float*)d_in[25];
  const float* dcqw = (const float*)d_in[26];
  const float* dcqb = (const float*)d_in[27];
  const float* dcow = (const float*)d_in[28];
  const float* dcob = (const float*)d_in[29];
  const float* dl1w = (const float*)d_in[30];
  const float* dl1b = (const float*)d_in[31];
  const float* dl2w = (const float*)d_in[32];
  const float* dl2b = (const float*)d_in[33];
  const float* dl3w = (const float*)d_in[34];
  const float* dl3b = (const float*)d_in[35];
  const float* df1w = (const float*)d_in[36];
  const float* df1b = (const float*)d_in[37];
  const float* df2w = (const float*)d_in[38];
  const float* df2b = (const float*)d_in[39];
  const float* wc   = (const float*)d_in[40];
  const float* bc   = (const float*)d_in[41];
  const float* wsg  = (const float*)d_in[42];
  const float* bsg  = (const float*)d_in[43];

  const size_t NE = 37632;   // F*B*SEQ
  const size_t ND = 10752;   // F*B*PRED
  auto al = [](size_t x) { return (x + 255) & ~(size_t)255; };

  size_t fixedB = al(NE * 1024) + al(ND * 1024) + al(ND * 64) + al(ND * 4);
  int G = 0;
  for (int g = 7; g >= 1; --g) {
    size_t need = fixedB
        + al((size_t)g * 5376 * 2048 * 2)
        + al((size_t)g * 5376 * 512 * 2)
        + al((size_t)g * 2048 * 512 * 2)
        + al((size_t)g * 1536 * 512 * 2);
    if (need <= ws_size) { G = g; break; }
  }
  if (G == 0) {
    diag_kernel<<<dim3((out_size + 255) / 256), 256, 0, stream>>>(
        (float*)d_out, 1000.0f + (float)(ws_size >> 20), out_size);
    return;
  }

  char* base = (char*)d_ws;
  size_t off = 0;
  auto alloc = [&](size_t bytes) -> void* { void* r = base + off; off += al(bytes); return r; };
  u16*   hres = (u16*)  alloc(NE * 1024);
  u16*   tres = (u16*)  alloc(ND * 1024);
  float* cb   = (float*)alloc(ND * 64);
  float* sg   = (float*)alloc(ND * 4);
  u16*   bigc = (u16*)  alloc((size_t)G * 5376 * 2048 * 2);
  u16*   aobc = (u16*)  alloc((size_t)G * 5376 * 512 * 2);
  u16*   wbuf = (u16*)  alloc((size_t)G * 2048 * 512 * 2);
  u16*   memb = (u16*)  alloc((size_t)G * 1536 * 512 * 2);

  embed_enc_k<<<dim3(37632), 128, 0, stream>>>(batch_x, batch_x_mark, w_in, b_in, hres);
  embed_dec_k<<<dim3(10752), 128, 0, stream>>>(batch_y_mark, w_co, b_co, tres);

  auto cvtw = [&](const float* src, long n_per_f, long f_stride, int g) {
    cvt_w_kernel<<<dim3(512), 256, 0, stream>>>(src, wbuf, n_per_f, f_stride,
                                                (long)g * n_per_f / 4);
  };
  auto gemm = [&](const u16* A, long sAz, u16* C, long sCz, const float* bias, long sBias,
                  int M, int N, int K, int g, int relu) {
    dim3 gr(M / 256, N / 256, g);
    gemm_bf16<<<gr, 512, 0, stream>>>(A, wbuf, C, bias, M, N, K, sAz, (long)N * K, sCz,
                                      sBias, relu);
  };

  for (int f0 = 0; f0 < 7; f0 += G) {
    int g = (7 - f0 < G) ? (7 - f0) : G;
    u16* hc = hres + (size_t)f0 * 5376 * 512;
    u16* tc = tres + (size_t)f0 * 1536 * 512;

    // ---------------- encoder (EL = 2) ----------------
    for (int l = 0; l < 2; ++l) {
      cvtw(eqw + (size_t)f0 * 1572864 + (size_t)l * 786432, 786432L, 1572864L, g);
      gemm(hc, 5376L * 512, bigc, 5376L * 1536, eqb + f0 * 3072 + l * 1536, 3072,
           5376, 1536, 512, g, 0);
      attn_mfma<336, 112, 3><<<dim3(8, g * 16, 2), 256, 0, stream>>>(
          bigc, bigc + 512, bigc + 1024, aobc, 336, 1536, 1536, 0, 11);
      cvtw(eow + (size_t)f0 * 524288 + (size_t)l * 262144, 262144L, 524288L, g);
      gemm(aobc, 5376L * 512, bigc, 5376L * 512, eob + f0 * 1024 + l * 512, 1024,
           5376, 512, 512, g, 0);
      ln_kernel<<<dim3(g * 5376), 128, 0, stream>>>(
          hc, bigc, el1w + f0 * 1024 + l * 512, el1b + f0 * 1024 + l * 512, 5376, 1024);
      cvtw(ef1w + (size_t)f0 * 2097152 + (size_t)l * 1048576, 1048576L, 2097152L, g);
      gemm(hc, 5376L * 512, bigc, 5376L * 2048, ef1b + f0 * 4096 + l * 2048, 4096,
           5376, 2048, 512, g, 1);
      cvtw(ef2w + (size_t)f0 * 2097152 + (size_t)l * 1048576, 1048576L, 2097152L, g);
      gemm(bigc, 5376L * 2048, aobc, 5376L * 512, ef2b + f0 * 1024 + l * 512, 1024,
           5376, 512, 2048, g, 0);
      ln_kernel<<<dim3(g * 5376), 128, 0, stream>>>(
          hc, aobc, el2w + f0 * 1024 + l * 512, el2b + f0 * 1024 + l * 512, 5376, 1024);
    }

    mem_kernel<<<dim3(g * 16, 6), 256, 0, stream>>>(
        hc, elw + (size_t)f0 * 32256, elb + f0 * 96, memb);

    // ---------------- decoder (DL = 1) ----------------
    cvtw(dsqw + (size_t)f0 * 786432, 786432L, 786432L, g);
    gemm(tc, 1536L * 512, bigc, 1536L * 1536, dsqb + f0 * 1536, 1536,
         1536, 1536, 512, g, 0);
    attn_mfma<96, 96, 2><<<dim3(8, g * 16, 1), 256, 0, stream>>>(
        bigc, bigc + 512, bigc + 1024, aobc, 96, 1536, 1536, 1, 6);
    cvtw(dsow + (size_t)f0 * 262144, 262144L, 262144L, g);
    gemm(aobc, 1536L * 512, bigc, 1536L * 512, dsob + f0 * 512, 512,
         1536, 512, 512, g, 0);
    ln_kernel<<<dim3(g * 1536), 128, 0, stream>>>(
        tc, bigc, dl1w + f0 * 512, dl1b + f0 * 512, 1536, 512);

    cvtw(dcqw + (size_t)f0 * 786432, 262144L, 786432L, g);  // Wq rows 0..511
    gemm(tc, 1536L * 512, bigc, 1536L * 512, dcqb + f0 * 1536, 1536,
         1536, 512, 512, g, 0);
    u16* bigKV = bigc + (size_t)g * 1536 * 512;
    cvtw(dcqw + (size_t)f0 * 786432 + 262144, 524288L, 786432L, g);  // Wk,Wv
    gemm(memb, 1536L * 512, bigKV, 1536L * 1024, dcqb + f0 * 1536 + 512, 1536,
         1536, 1024, 512, g, 0);
    attn_mfma<96, 96, 2><<<dim3(8, g * 16, 1), 256, 0, stream>>>(
        bigc, bigKV, bigKV + 512, aobc, 96, 512, 1024, 0, 6);
    cvtw(dcow + (size_t)f0 * 262144, 262144L, 262144L, g);
    gemm(aobc, 1536L * 512, bigc, 1536L * 512, dcob + f0 * 512, 512,
         1536, 512, 512, g, 0);
    ln_kernel<<<dim3(g * 1536), 128, 0, stream>>>(
        tc, bigc, dl2w + f0 * 512, dl2b + f0 * 512, 1536, 512);

    cvtw(df1w + (size_t)f0 * 1048576, 1048576L, 1048576L, g);
    gemm(tc, 1536L * 512, bigc, 1536L * 2048, df1b + f0 * 2048, 2048,
         1536, 2048, 512, g, 1);
    cvtw(df2w + (size_t)f0 * 1048576, 1048576L, 1048576L, g);
    gemm(bigc, 1536L * 2048, aobc, 1536L * 512, df2b + f0 * 512, 512,
         1536, 512, 2048, g, 0);
    ln_kernel<<<dim3(g * 1536), 128, 0, stream>>>(
        tc, aobc, dl3w + f0 * 512, dl3b + f0 * 512, 1536, 512);

    head_kernel<<<dim3(g * 1536), 64, 0, stream>>>(tc, wc, bc, wsg, bsg, cb, sg, f0);
  }

  scan_kernel<<<dim3(7), 256, 0, stream>>>(cb, sg, (float*)d_out);
}

// Round 9
// 1544.799 us; speedup vs baseline: 4.9646x; 4.9646x over previous
//
#include <hip/hip_runtime.h>

typedef unsigned short u16;
typedef unsigned int   u32;
typedef __attribute__((ext_vector_type(8))) short short8;
typedef __attribute__((ext_vector_type(4))) float f32x4;

#define DEV static __device__ __forceinline__

DEV float bf2f(u16 u) { return __uint_as_float(((u32)u) << 16); }
DEV u16 f2bf(float f) {
  u32 u = __float_as_uint(f);
  return (u16)((u + 0x7fffu + ((u >> 16) & 1u)) >> 16);
}

#define GLD16(gp, lp) __builtin_amdgcn_global_load_lds( \
    (__attribute__((address_space(1))) u32*)(gp),       \
    (__attribute__((address_space(3))) u32*)(lp), 16, 0, 0)

#define SBAR()  asm volatile("s_barrier" ::: "memory")
#define LGKM0() asm volatile("s_waitcnt lgkmcnt(0)" ::: "memory")

// ---------------------------------------------------------------------------
// Grouped GEMM (round-7 verified): 256x256 tile, BK=64, 8 waves (2Mx4N),
// 4-phase half-tile schedule, counted vmcnt(4), T1/T2/T5, 128KB LDS,
// launch_bounds(512,2) — 112 VGPR + 128 AGPR = 240/wave, 1 block/CU.
// (LESSON r8: (512,4) caps regs at 128 < acc alone -> total spill. Never.)
// Used for large grids (enc QKV, enc FFN1). M%256==0, N%256==0, K%64, K>=128.
// ---------------------------------------------------------------------------
__global__ __launch_bounds__(512, 2) void gemm_bf16(
    const u16* __restrict__ A, const u16* __restrict__ Bw, u16* __restrict__ C,
    const float* __restrict__ bias, int M, int N, int K,
    long sAz, long sBz, long sCz, long sBiasZ, int relu)
{
  __shared__ __align__(16) u16 Asm[2][2][8192];   // [dbuf][half][128*64]
  __shared__ __align__(16) u16 Bsm[2][2][8192];

  int gx = (int)gridDim.x, gy = (int)gridDim.y;
  int nwg = gx * gy * (int)gridDim.z;
  int orig = (int)blockIdx.x + gx * ((int)blockIdx.y + gy * (int)blockIdx.z);
  int qq = nwg >> 3, rr_ = nwg & 7;
  int xcd = orig & 7, pos = orig >> 3;
  int lg_id = (xcd < rr_) ? (xcd * (qq + 1) + pos) : (rr_ * (qq + 1) + (xcd - rr_) * qq + pos);
  int bz = lg_id / (gx * gy);
  int rem = lg_id - bz * (gx * gy);
  int by = rem / gx, bx = rem - by * gx;

  A += (size_t)bz * sAz; Bw += (size_t)bz * sBz; C += (size_t)bz * sCz; bias += (size_t)bz * sBiasZ;
  int tileM = bx * 256, tileN = by * 256;
  int tid = threadIdx.x, wave = tid >> 6, lane = tid & 63;
  int lr = lane & 15, lgp = lane >> 4;
  int wm = (wave >> 2) * 128;
  int wn = (wave & 3) * 64;
  int ah = wave >> 2;
  int bh = (wave & 3) >> 1;
  int bnb = ((wave & 3) & 1) * 64;

  const int NT = K >> 6;
  const u16* Abase = A + (size_t)tileM * K;
  const u16* Bbase = Bw + (size_t)tileN * K;

  auto SA = [&](int b, int h, int t) {
    const u16* src = Abase + (size_t)h * 128 * K + t * 64;
    #pragma unroll
    for (int i = 0; i < 2; i++) {
      int gi = i * 512 + tid;
      int row = gi >> 3, g = gi & 7;
      GLD16(src + (size_t)row * K + ((g ^ (row & 7)) * 8), Asm[b][h] + (size_t)gi * 8);
    }
  };
  auto SB = [&](int b, int h, int t) {
    const u16* src = Bbase + (size_t)h * 128 * K + t * 64;
    #pragma unroll
    for (int i = 0; i < 2; i++) {
      int gi = i * 512 + tid;
      int row = gi >> 3, g = gi & 7;
      GLD16(src + (size_t)row * K + ((g ^ (row & 7)) * 8), Bsm[b][h] + (size_t)gi * 8);
    }
  };

  f32x4 acc[8][4] = {};

  SA(0, 0, 0); SA(0, 1, 0); SB(0, 0, 0); SB(0, 1, 0);
  if (NT > 1) { SB(1, 0, 1); SB(1, 1, 1); }
  if (NT > 1) asm volatile("s_waitcnt vmcnt(4)" ::: "memory");
  else        asm volatile("s_waitcnt vmcnt(0)" ::: "memory");
  SBAR();

  for (int t = 0; t < NT; ++t) {
    int cur = t & 1;
    const u16* Aslot = Asm[cur][ah];
    const u16* Bslot = Bsm[cur][bh];
    short8 afr[8], b0[4], b1[4];

    // phase 0: read A(m0-3)+B(n0-1); stage A0(t+1)
    #pragma unroll
    for (int mm = 0; mm < 4; ++mm) {
      int rw = mm * 16 + lr;
      #pragma unroll
      for (int ks = 0; ks < 2; ++ks)
        afr[mm * 2 + ks] = *(const short8*)(Aslot + rw * 64 + (((ks * 4 + lgp) ^ (rw & 7)) * 8));
    }
    #pragma unroll
    for (int nn = 0; nn < 2; ++nn) {
      int rw = bnb + nn * 16 + lr;
      #pragma unroll
      for (int ks = 0; ks < 2; ++ks)
        b0[nn * 2 + ks] = *(const short8*)(Bslot + rw * 64 + (((ks * 4 + lgp) ^ (rw & 7)) * 8));
    }
    if (t + 1 < NT) SA(cur ^ 1, 0, t + 1);
    SBAR(); LGKM0();
    __builtin_amdgcn_s_setprio(1);
    #pragma unroll
    for (int mm = 0; mm < 4; ++mm)
      #pragma unroll
      for (int nn = 0; nn < 2; ++nn)
        #pragma unroll
        for (int ks = 0; ks < 2; ++ks)
          acc[mm][nn] = __builtin_amdgcn_mfma_f32_16x16x32_bf16(
              afr[mm * 2 + ks], b0[nn * 2 + ks], acc[mm][nn], 0, 0, 0);
    __builtin_amdgcn_s_setprio(0);
    SBAR();

    // phase 1: read B(n2-3); stage A1(t+1)
    #pragma unroll
    for (int nn = 0; nn < 2; ++nn) {
      int rw = bnb + (nn + 2) * 16 + lr;
      #pragma unroll
      for (int ks = 0; ks < 2; ++ks)
        b1[nn * 2 + ks] = *(const short8*)(Bslot + rw * 64 + (((ks * 4 + lgp) ^ (rw & 7)) * 8));
    }
    if (t + 1 < NT) SA(cur ^ 1, 1, t + 1);
    SBAR(); LGKM0();
    __builtin_amdgcn_s_setprio(1);
    #pragma unroll
    for (int mm = 0; mm < 4; ++mm)
      #pragma unroll
      for (int nn = 0; nn < 2; ++nn)
        #pragma unroll
        for (int ks = 0; ks < 2; ++ks)
          acc[mm][nn + 2] = __builtin_amdgcn_mfma_f32_16x16x32_bf16(
              afr[mm * 2 + ks], b1[nn * 2 + ks], acc[mm][nn + 2], 0, 0, 0);
    __builtin_amdgcn_s_setprio(0);
    SBAR();

    // phase 2: read A(m4-7); stage B0(t+2)
    #pragma unroll
    for (int mm = 0; mm < 4; ++mm) {
      int rw = (mm + 4) * 16 + lr;
      #pragma unroll
      for (int ks = 0; ks < 2; ++ks)
        afr[mm * 2 + ks] = *(const short8*)(Aslot + rw * 64 + (((ks * 4 + lgp) ^ (rw & 7)) * 8));
    }
    if (t + 2 < NT) SB(cur, 0, t + 2);
    SBAR(); LGKM0();
    __builtin_amdgcn_s_setprio(1);
    #pragma unroll
    for (int mm = 0; mm < 4; ++mm)
      #pragma unroll
      for (int nn = 0; nn < 2; ++nn)
        #pragma unroll
        for (int ks = 0; ks < 2; ++ks)
          acc[mm + 4][nn + 2] = __builtin_amdgcn_mfma_f32_16x16x32_bf16(
              afr[mm * 2 + ks], b1[nn * 2 + ks], acc[mm + 4][nn + 2], 0, 0, 0);
    __builtin_amdgcn_s_setprio(0);
    SBAR();

    // phase 3: stage B1(t+2); Q10 (regs only); tile boundary
    if (t + 2 < NT) SB(cur, 1, t + 2);
    __builtin_amdgcn_s_setprio(1);
    #pragma unroll
    for (int mm = 0; mm < 4; ++mm)
      #pragma unroll
      for (int nn = 0; nn < 2; ++nn)
        #pragma unroll
        for (int ks = 0; ks < 2; ++ks)
          acc[mm + 4][nn] = __builtin_amdgcn_mfma_f32_16x16x32_bf16(
              afr[mm * 2 + ks], b0[nn * 2 + ks], acc[mm + 4][nn], 0, 0, 0);
    __builtin_amdgcn_s_setprio(0);
    if (t + 2 < NT) asm volatile("s_waitcnt vmcnt(4)" ::: "memory");
    else            asm volatile("s_waitcnt vmcnt(0)" ::: "memory");
    SBAR();
  }

  float bb[4];
  #pragma unroll
  for (int n = 0; n < 4; ++n) bb[n] = bias[tileN + wn + n * 16 + lr];
  #pragma unroll
  for (int m = 0; m < 8; ++m) {
    #pragma unroll
    for (int rr = 0; rr < 4; ++rr) {
      int mrow = tileM + wm + m * 16 + lgp * 4 + rr;
      u16* crow = C + (size_t)mrow * N + tileN + wn + lr;
      #pragma unroll
      for (int n = 0; n < 4; ++n) {
        float v = acc[m][n][rr] + bb[n];
        if (relu) v = fmaxf(v, 0.f);
        crow[n * 16] = f2bf(v);
      }
    }
  }
}

// ---------------------------------------------------------------------------
// Variant GEMM for tail-prone grids: 128x256 tile, 4 waves (256 thr), BK=32,
// double-buffered, counted vmcnt(6). 48KB LDS + 228 regs/wave
// (launch_bounds(256,2) -> 256-reg cap, no spill) => 2 blocks/CU, overlap
// via co-residency (m114). Swizzle for 64B rows: slot = lgp ^ ((row>>1)&3)
// (uniform 8 lanes/bank-quad); staging pre-applies same XOR to global src.
// M%128==0, N%256==0, K%32==0, K>=64.
// ---------------------------------------------------------------------------
__global__ __launch_bounds__(256, 2) void gemm_bf16_v(
    const u16* __restrict__ A, const u16* __restrict__ Bw, u16* __restrict__ C,
    const float* __restrict__ bias, int M, int N, int K,
    long sAz, long sBz, long sCz, long sBiasZ, int relu)
{
  __shared__ __align__(16) u16 Asm[2][128 * 32];
  __shared__ __align__(16) u16 Bsm[2][256 * 32];

  int gx = (int)gridDim.x, gy = (int)gridDim.y;
  int nwg = gx * gy * (int)gridDim.z;
  int orig = (int)blockIdx.x + gx * ((int)blockIdx.y + gy * (int)blockIdx.z);
  int qq = nwg >> 3, rr_ = nwg & 7;
  int xcd = orig & 7, pos = orig >> 3;
  int lg_id = (xcd < rr_) ? (xcd * (qq + 1) + pos) : (rr_ * (qq + 1) + (xcd - rr_) * qq + pos);
  int bz = lg_id / (gx * gy);
  int rem = lg_id - bz * (gx * gy);
  int by = rem / gx, bx = rem - by * gx;

  A += (size_t)bz * sAz; Bw += (size_t)bz * sBz; C += (size_t)bz * sCz; bias += (size_t)bz * sBiasZ;
  int tileM = bx * 128, tileN = by * 256;
  int tid = threadIdx.x, lane = tid & 63;
  int wave = tid >> 6;
  int lr = lane & 15, lgp = lane >> 4;
  int wn = wave * 64;

  const int NT = K >> 5;
  const u16* Abase = A + (size_t)tileM * K;
  const u16* Bbase = Bw + (size_t)tileN * K;

  // stage tile t (A 8KB: 2 issues/thread; B 16KB: 4 issues/thread) = 6 vmcnt
  auto STAGE = [&](int b, int t) {
    int kb = t * 32;
    #pragma unroll
    for (int i = 0; i < 2; i++) {
      int gi = i * 256 + tid;
      int row = gi >> 2, g = gi & 3;
      GLD16(Abase + (size_t)row * K + kb + ((g ^ ((row >> 1) & 3)) * 8),
            Asm[b] + (size_t)gi * 8);
    }
    #pragma unroll
    for (int i = 0; i < 4; i++) {
      int gi = i * 256 + tid;
      int row = gi >> 2, g = gi & 3;
      GLD16(Bbase + (size_t)row * K + kb + ((g ^ ((row >> 1) & 3)) * 8),
            Bsm[b] + (size_t)gi * 8);
    }
  };

  f32x4 acc[8][4] = {};

  STAGE(0, 0);
  if (NT > 1) STAGE(1, 1);

  for (int t = 0; t < NT; ++t) {
    int cur = t & 1;
    if (t + 1 < NT) asm volatile("s_waitcnt vmcnt(6)" ::: "memory");
    else            asm volatile("s_waitcnt vmcnt(0)" ::: "memory");
    SBAR();

    const u16* Ab = Asm[cur];
    const u16* Bb = Bsm[cur];
    short8 afr[8], bfr[4];
    #pragma unroll
    for (int m = 0; m < 8; ++m) {
      int rw = m * 16 + lr;
      afr[m] = *(const short8*)(Ab + rw * 32 + ((lgp ^ ((rw >> 1) & 3)) * 8));
    }
    #pragma unroll
    for (int n = 0; n < 4; ++n) {
      int rw = wn + n * 16 + lr;
      bfr[n] = *(const short8*)(Bb + rw * 32 + ((lgp ^ ((rw >> 1) & 3)) * 8));
    }
    __builtin_amdgcn_s_setprio(1);
    #pragma unroll
    for (int m = 0; m < 8; ++m)
      #pragma unroll
      for (int n = 0; n < 4; ++n)
        acc[m][n] = __builtin_amdgcn_mfma_f32_16x16x32_bf16(
            afr[m], bfr[n], acc[m][n], 0, 0, 0);
    __builtin_amdgcn_s_setprio(0);
    LGKM0();
    SBAR();
    if (t + 2 < NT) STAGE(cur, t + 2);
  }

  float bb[4];
  #pragma unroll
  for (int n = 0; n < 4; ++n) bb[n] = bias[tileN + wn + n * 16 + lr];
  #pragma unroll
  for (int m = 0; m < 8; ++m) {
    #pragma unroll
    for (int rr = 0; rr < 4; ++rr) {
      int mrow = tileM + m * 16 + lgp * 4 + rr;
      u16* crow = C + (size_t)mrow * N + tileN + wn + lr;
      #pragma unroll
      for (int n = 0; n < 4; ++n) {
        float v = acc[m][n][rr] + bb[n];
        if (relu) v = fmaxf(v, 0.f);
        crow[n * 16] = f2bf(v);
      }
    }
  }
}

// ---------------------------------------------------------------------------
// fp32 -> bf16 weight slice conversion
// ---------------------------------------------------------------------------
__global__ void cvt_w_kernel(const float* __restrict__ src, u16* __restrict__ dst,
                             long n_per_f, long f_stride, long total4)
{
  long i = (long)blockIdx.x * blockDim.x + threadIdx.x;
  long step = (long)gridDim.x * blockDim.x;
  for (; i < total4; i += step) {
    long e = i * 4;
    long f = e / n_per_f; long r = e - f * n_per_f;
    float4 v = *(const float4*)(src + f * f_stride + r);
    *(ushort4*)(dst + e) = make_ushort4(f2bf(v.x), f2bf(v.y), f2bf(v.z), f2bf(v.w));
  }
}

// ---------------------------------------------------------------------------
// Embeddings (unchanged)
// ---------------------------------------------------------------------------
__global__ __launch_bounds__(128) void embed_enc_k(
    const float* __restrict__ x, const float* __restrict__ mark,
    const float* __restrict__ w_in, const float* __restrict__ b_in,
    u16* __restrict__ hb)
{
  int row = blockIdx.x;
  int f = row / 5376; int rem = row - f * 5376; int b = rem / 336; int s = rem - b * 336;
  int bsix = b * 336 + s;
  float v0 = x[(size_t)bsix * 7 + f];
  float m0 = mark[(size_t)bsix * 4 + 0], m1 = mark[(size_t)bsix * 4 + 1];
  float m2 = mark[(size_t)bsix * 4 + 2], m3 = mark[(size_t)bsix * 4 + 3];
  int d0 = threadIdx.x * 4;
  u16 ob[4];
  #pragma unroll
  for (int c = 0; c < 4; c++) {
    int d = d0 + c;
    const float* w = w_in + d * 5;
    float val = w[0] * v0 + w[1] * m0 + w[2] * m1 + w[3] * m2 + w[4] * m3 + b_in[d];
    int i = d >> 1;
    float dv = expf((float)i * -0.0359778920778f);
    float arg = (float)s * dv;
    val += (d & 1) ? cosf(arg) : sinf(arg);
    ob[c] = f2bf(val);
  }
  *(ushort4*)(hb + (size_t)row * 512 + d0) = make_ushort4(ob[0], ob[1], ob[2], ob[3]);
}

__global__ __launch_bounds__(128) void embed_dec_k(
    const float* __restrict__ ymark, const float* __restrict__ w_co,
    const float* __restrict__ b_co, u16* __restrict__ tb)
{
  int row = blockIdx.x;
  int f = row / 1536; int rem = row - f * 1536; int b = rem / 96; int pp = rem - b * 96;
  int bp = b * 96 + pp;
  float m0 = ymark[(size_t)bp * 4 + 0], m1 = ymark[(size_t)bp * 4 + 1];
  float m2 = ymark[(size_t)bp * 4 + 2], m3 = ymark[(size_t)bp * 4 + 3];
  int d0 = threadIdx.x * 4;
  u16 ob[4];
  #pragma unroll
  for (int c = 0; c < 4; c++) {
    int d = d0 + c;
    const float* w = w_co + d * 4;
    float val = w[0] * m0 + w[1] * m1 + w[2] * m2 + w[3] * m3 + b_co[d];
    int i = d >> 1;
    float dv = expf((float)i * -0.0359778920778f);
    float arg = (float)pp * dv;
    val += (d & 1) ? cosf(arg) : sinf(arg);
    ob[c] = f2bf(val);
  }
  *(ushort4*)(tb + (size_t)row * 512 + d0) = make_ushort4(ob[0], ob[1], ob[2], ob[3]);
}

// ---------------------------------------------------------------------------
// MFMA attention (unchanged — passing)
// ---------------------------------------------------------------------------
template<int LK, int CHUNK, int NQI>
__global__ __launch_bounds__(256) void attn_mfma(
    const u16* __restrict__ q, const u16* __restrict__ k, const u16* __restrict__ v,
    u16* __restrict__ out, int Lq, int qstride, int kvstride, int causal, int qspan)
{
  constexpr int NCH = LK / CHUNK;
  constexpr int NKT = CHUNK / 16;
  constexpr int NKS = (CHUNK + 31) / 32;
  constexpr int KPAD = NKS * 32;
  constexpr int VSTR = KPAD + 8;
  constexpr int NGRP = CHUNK * 8 / 64;

  __shared__ __align__(16) u16 KsS[CHUNK * 64];
  __shared__ __align__(16) u16 VtS[64 * VSTR];
  __shared__ __align__(16) u16 PWS[4][16 * VSTR];

  int hh = blockIdx.x, fb = blockIdx.y;
  int tid = threadIdx.x, wave = tid >> 6, lane = tid & 63;
  int lr = lane & 15, lg = lane >> 4;

  const int nqt = Lq / 16;
  const int qlo = (int)blockIdx.z * qspan;
  const int qhi = (qlo + qspan < nqt) ? (qlo + qspan) : nqt;

  const u16* qp = q + (size_t)fb * Lq * qstride + hh * 64;
  const u16* kp = k + (size_t)fb * LK * kvstride + hh * 64;
  const u16* vp = v + (size_t)fb * LK * kvstride + hh * 64;

  if constexpr (KPAD > CHUNK) {
    constexpr int TW = KPAD - CHUNK;
    for (int i = tid; i < 64 * TW; i += 256)
      VtS[(i / TW) * VSTR + CHUNK + (i % TW)] = 0;
    u16* PW = PWS[wave];
    for (int i = lane; i < 16 * TW; i += 64)
      PW[(i / TW) * VSTR + CHUNK + (i % TW)] = 0;
  }

  f32x4 oacc[NQI][4] = {};
  f32x4 lsum[NQI] = {};
  u16* PW = PWS[wave];

  for (int c = 0; c < NCH; ++c) {
    __syncthreads();

    const u16* kcp = kp + (size_t)c * CHUNK * kvstride;
    for (int grp = wave; grp < NGRP; grp += 4) {
      int gi = grp * 64 + lane;
      int row = gi >> 3, g = gi & 7;
      GLD16(kcp + (size_t)row * kvstride + ((g ^ (row & 7)) * 8), KsS + (size_t)gi * 8);
    }
    const u16* vcp = vp + (size_t)c * CHUNK * kvstride;
    for (int idx = tid; idx < CHUNK * 8; idx += 256) {
      int kk = idx >> 3, dg = idx & 7;
      uint4 pv = *(const uint4*)(vcp + (size_t)kk * kvstride + dg * 8);
      u16* col = VtS + (size_t)(dg * 8) * VSTR + kk;
      col[0 * VSTR] = (u16)pv.x; col[1 * VSTR] = (u16)(pv.x >> 16);
      col[2 * VSTR] = (u16)pv.y; col[3 * VSTR] = (u16)(pv.y >> 16);
      col[4 * VSTR] = (u16)pv.z; col[5 * VSTR] = (u16)(pv.z >> 16);
      col[6 * VSTR] = (u16)pv.w; col[7 * VSTR] = (u16)(pv.w >> 16);
    }
    __syncthreads();

    #pragma unroll
    for (int qi = 0; qi < NQI; ++qi) {
      int qt = qlo + wave + qi * 4;
      if (qt < qhi) {
        const u16* qrow = qp + (size_t)(qt * 16 + lr) * qstride + lg * 8;
        short8 qf0 = *(const short8*)(qrow);
        short8 qf1 = *(const short8*)(qrow + 32);

        f32x4 sacc[NKT];
        #pragma unroll
        for (int t = 0; t < NKT; t++) {
          int row = t * 16 + lr;
          const u16* kb = KsS + row * 64;
          short8 kf0 = *(const short8*)(kb + ((lg ^ (row & 7)) * 8));
          short8 kf1 = *(const short8*)(kb + (((lg + 4) ^ (row & 7)) * 8));
          f32x4 s = {0.f, 0.f, 0.f, 0.f};
          s = __builtin_amdgcn_mfma_f32_16x16x32_bf16(qf0, kf0, s, 0, 0, 0);
          s = __builtin_amdgcn_mfma_f32_16x16x32_bf16(qf1, kf1, s, 0, 0, 0);
          sacc[t] = s;
        }

        #pragma unroll
        for (int t = 0; t < NKT; t++) {
          int kg = c * CHUNK + t * 16 + lr;
          #pragma unroll
          for (int r = 0; r < 4; r++) {
            int qg = qt * 16 + lg * 4 + r;
            float p = (causal && kg > qg) ? 0.f : __expf(sacc[t][r] * 0.125f);
            sacc[t][r] = p;
            lsum[qi][r] += p;
          }
          u16* pw = PW + (size_t)(lg * 4) * VSTR + t * 16 + lr;
          pw[0 * VSTR] = f2bf(sacc[t][0]);
          pw[1 * VSTR] = f2bf(sacc[t][1]);
          pw[2 * VSTR] = f2bf(sacc[t][2]);
          pw[3 * VSTR] = f2bf(sacc[t][3]);
        }

        #pragma unroll
        for (int s = 0; s < NKS; s++) {
          short8 pf = *(const short8*)(PW + (size_t)lr * VSTR + s * 32 + lg * 8);
          #pragma unroll
          for (int j = 0; j < 4; j++) {
            short8 vf = *(const short8*)(VtS + (size_t)(j * 16 + lr) * VSTR + s * 32 + lg * 8);
            oacc[qi][j] = __builtin_amdgcn_mfma_f32_16x16x32_bf16(pf, vf, oacc[qi][j], 0, 0, 0);
          }
        }
      }
    }
  }

  #pragma unroll
  for (int qi = 0; qi < NQI; ++qi) {
    int qt = qlo + wave + qi * 4;
    if (qt < qhi) {
      float l0 = lsum[qi][0], l1 = lsum[qi][1], l2 = lsum[qi][2], l3 = lsum[qi][3];
      #pragma unroll
      for (int m = 1; m < 16; m <<= 1) {
        l0 += __shfl_xor(l0, m);
        l1 += __shfl_xor(l1, m);
        l2 += __shfl_xor(l2, m);
        l3 += __shfl_xor(l3, m);
      }
      float inv[4] = {1.f / l0, 1.f / l1, 1.f / l2, 1.f / l3};
      #pragma unroll
      for (int r = 0; r < 4; r++) {
        size_t orow = (size_t)fb * Lq + qt * 16 + lg * 4 + r;
        u16* ob = out + orow * 512 + hh * 64 + lr;
        #pragma unroll
        for (int j = 0; j < 4; j++)
          ob[j * 16] = f2bf(oacc[qi][j][r] * inv[r]);
      }
    }
  }
}

// ---------------------------------------------------------------------------
// Residual add + LayerNorm (unchanged)
// ---------------------------------------------------------------------------
__global__ __launch_bounds__(128) void ln_kernel(
    u16* __restrict__ h, const u16* __restrict__ delta,
    const float* __restrict__ gamma, const float* __restrict__ beta,
    int rows_per_f, long gstride)
{
  __shared__ float red[2];
  int row = blockIdx.x;
  int f = row / rows_per_f;
  const float* g = gamma + (size_t)f * gstride;
  const float* be = beta + (size_t)f * gstride;
  int d0 = threadIdx.x * 4;
  size_t p = (size_t)row * 512 + d0;
  ushort4 hv = *(const ushort4*)(h + p);
  ushort4 dv = *(const ushort4*)(delta + p);
  float x0 = bf2f(hv.x) + bf2f(dv.x), x1 = bf2f(hv.y) + bf2f(dv.y);
  float x2 = bf2f(hv.z) + bf2f(dv.z), x3 = bf2f(hv.w) + bf2f(dv.w);
  float ssum = x0 + x1 + x2 + x3;
  #pragma unroll
  for (int m = 1; m < 64; m <<= 1) ssum += __shfl_xor(ssum, m);
  if ((threadIdx.x & 63) == 0) red[threadIdx.x >> 6] = ssum;
  __syncthreads();
  float mean = (red[0] + red[1]) * (1.f / 512.f);
  __syncthreads();
  float c0 = x0 - mean, c1 = x1 - mean, c2 = x2 - mean, c3 = x3 - mean;
  float sq = c0 * c0 + c1 * c1 + c2 * c2 + c3 * c3;
  #pragma unroll
  for (int m = 1; m < 64; m <<= 1) sq += __shfl_xor(sq, m);
  if ((threadIdx.x & 63) == 0) red[threadIdx.x >> 6] = sq;
  __syncthreads();
  float var = (red[0] + red[1]) * (1.f / 512.f);
  float rstd = rsqrtf(var + 1e-5f);
  float y0 = c0 * rstd * g[d0 + 0] + be[d0 + 0];
  float y1 = c1 * rstd * g[d0 + 1] + be[d0 + 1];
  float y2 = c2 * rstd * g[d0 + 2] + be[d0 + 2];
  float y3 = c3 * rstd * g[d0 + 3] + be[d0 + 3];
  *(ushort4*)(h + p) = make_ushort4(f2bf(y0), f2bf(y1), f2bf(y2), f2bf(y3));
}

// ---------------------------------------------------------------------------
// mem projection (unchanged)
// ---------------------------------------------------------------------------
__global__ __launch_bounds__(256) void mem_kernel(
    const u16* __restrict__ h, const float* __restrict__ elw,
    const float* __restrict__ elb, u16* __restrict__ memb)
{
  int fb = blockIdx.x; int f = fb >> 4;
  int pc = blockIdx.y;
  int d0 = threadIdx.x * 2;
  const u16* hbase = h + (size_t)fb * 336 * 512;
  const float* wbase = elw + (size_t)f * 96 * 336 + (size_t)pc * 16 * 336;
  float a0[16], a1[16];
  #pragma unroll
  for (int pp = 0; pp < 16; pp++) { a0[pp] = 0.f; a1[pp] = 0.f; }
  for (int s = 0; s < 336; s++) {
    ushort2 h2 = *(const ushort2*)(hbase + (size_t)s * 512 + d0);
    float hx = bf2f(h2.x), hy = bf2f(h2.y);
    #pragma unroll
    for (int pp = 0; pp < 16; pp++) {
      float w = wbase[pp * 336 + s];
      a0[pp] += w * hx; a1[pp] += w * hy;
    }
  }
  #pragma unroll
  for (int pp = 0; pp < 16; pp++) {
    int pidx = pc * 16 + pp;
    size_t row = (size_t)fb * 96 + pidx;
    float e = elb[f * 96 + pidx];
    *(ushort2*)(memb + row * 512 + d0) = make_ushort2(f2bf(a0[pp] + e), f2bf(a1[pp] + e));
  }
}

// ---------------------------------------------------------------------------
// Output head (unchanged)
// ---------------------------------------------------------------------------
__global__ __launch_bounds__(64) void head_kernel(
    const u16* __restrict__ td, const float* __restrict__ wcp, const float* __restrict__ bcp,
    const float* __restrict__ wsp, const float* __restrict__ bsp,
    float* __restrict__ cb, float* __restrict__ sg, int f0)
{
  int rl = blockIdx.x, lane = threadIdx.x;
  size_t row = (size_t)f0 * 1536 + rl;
  const u16* x = td + (size_t)rl * 512;
  float xr[8];
  #pragma unroll
  for (int j = 0; j < 8; j++) xr[j] = bf2f(x[lane + 64 * j]);
  #pragma unroll
  for (int o = 0; o < 16; o++) {
    const float* w = wcp + o * 512;
    float p = 0.f;
    #pragma unroll
    for (int j = 0; j < 8; j++) p += xr[j] * w[lane + 64 * j];
    #pragma unroll
    for (int m = 1; m < 64; m <<= 1) p += __shfl_xor(p, m);
    if (lane == 0) {
      float cv = (p + bcp[o]) / 6.0f + 0.5f;
      cb[row * 16 + o] = fminf(fmaxf(cv, 0.f), 1.f);
    }
  }
  float p = 0.f;
  #pragma unroll
  for (int j = 0; j < 8; j++) p += xr[j] * wsp[lane + 64 * j];
  #pragma unroll
  for (int m = 1; m < 64; m <<= 1) p += __shfl_xor(p, m);
  if (lane == 0) {
    float zv = p + bsp[0];
    sg[row] = (zv > 20.f) ? zv : log1pf(expf(zv));
  }
}

// ---------------------------------------------------------------------------
// TAO scan (unchanged)
// ---------------------------------------------------------------------------
__global__ __launch_bounds__(256) void scan_kernel(
    const float* __restrict__ cbuf, const float* __restrict__ sgb, float* __restrict__ outp)
{
  int f = blockIdx.x;
  int b = threadIdx.x >> 4;
  int s = threadIdx.x & 15;
  size_t rbase = ((size_t)f * 16 + b) * 96;
  float a = cbuf[rbase * 16 + s];
  for (int p = 0; p < 96; ++p) {
    float cd = cbuf[(rbase + p) * 16 + s];
    float sd = sgb[rbase + p];
    float xs = (s >= 1 && s <= 14) ? a : 0.f;
    #pragma unroll
    for (int m = 1; m < 16; m <<= 1) xs += __shfl_xor(xs, m);
    float up = __shfl_up(a, 1, 16);
    float an = (s == 0) ? (a + cd) : ((s == 1) ? (cd - xs) : (up + cd));
    a = an;
    float y01 = __shfl(a, 0, 16) + __shfl(a, 1, 16) + sd;
    if (s == 0) outp[((size_t)b * 96 + p) * 7 + f] = y01;
  }
}

__global__ void diag_kernel(float* __restrict__ out, float v, int n)
{
  int i = blockIdx.x * 256 + threadIdx.x;
  if (i < n) out[i] = v;
}

// ---------------------------------------------------------------------------
extern "C" void kernel_launch(void* const* d_in, const int* in_sizes, int n_in,
                              void* d_out, int out_size, void* d_ws, size_t ws_size,
                              hipStream_t stream)
{
  (void)in_sizes; (void)n_in;
  const float* batch_x      = (const float*)d_in[0];
  const float* batch_x_mark = (const float*)d_in[1];
  const float* batch_y_mark = (const float*)d_in[3];
  const float* w_in = (const float*)d_in[4];
  const float* b_in = (const float*)d_in[5];
  const float* w_co = (const float*)d_in[6];
  const float* b_co = (const float*)d_in[7];
  const float* eqw  = (const float*)d_in[8];
  const float* eqb  = (const float*)d_in[9];
  const float* eow  = (const float*)d_in[10];
  const float* eob  = (const float*)d_in[11];
  const float* el1w = (const float*)d_in[12];
  const float* el1b = (const float*)d_in[13];
  const float* el2w = (const float*)d_in[14];
  const float* el2b = (const float*)d_in[15];
  const float* ef1w = (const float*)d_in[16];
  const float* ef1b = (const float*)d_in[17];
  const float* ef2w = (const float*)d_in[18];
  const float* ef2b = (const float*)d_in[19];
  const float* elw  = (const float*)d_in[20];
  const float* elb  = (const float*)d_in[21];
  const float* dsqw = (const float*)d_in[22];
  const float* dsqb = (const float*)d_in[23];
  const float* dsow = (const float*)d_in[24];
  const float* dsob = (const float*)d_in[25];
  const float* dcqw = (const float*)d_in[26];
  const float* dcqb = (const float*)d_in[27];
  const float* dcow = (const float*)d_in[28];
  const float* dcob = (const float*)d_in[29];
  const float* dl1w = (const float*)d_in[30];
  const float* dl1b = (const float*)d_in[31];
  const float* dl2w = (const float*)d_in[32];
  const float* dl2b = (const float*)d_in[33];
  const float* dl3w = (const float*)d_in[34];
  const float* dl3b = (const float*)d_in[35];
  const float* df1w = (const float*)d_in[36];
  const float* df1b = (const float*)d_in[37];
  const float* df2w = (const float*)d_in[38];
  const float* df2b = (const float*)d_in[39];
  const float* wc   = (const float*)d_in[40];
  const float* bc   = (const float*)d_in[41];
  const float* wsg  = (const float*)d_in[42];
  const float* bsg  = (const float*)d_in[43];

  const size_t NE = 37632;   // F*B*SEQ
  const size_t ND = 10752;   // F*B*PRED
  auto al = [](size_t x) { return (x + 255) & ~(size_t)255; };

  size_t fixedB = al(NE * 1024) + al(ND * 1024) + al(ND * 64) + al(ND * 4);
  int G = 0;
  for (int g = 7; g >= 1; --g) {
    size_t need = fixedB
        + al((size_t)g * 5376 * 2048 * 2)
        + al((size_t)g * 5376 * 512 * 2)
        + al((size_t)g * 2048 * 512 * 2)
        + al((size_t)g * 1536 * 512 * 2);
    if (need <= ws_size) { G = g; break; }
  }
  if (G == 0) {
    diag_kernel<<<dim3((out_size + 255) / 256), 256, 0, stream>>>(
        (float*)d_out, 1000.0f + (float)(ws_size >> 20), out_size);
    return;
  }

  char* base = (char*)d_ws;
  size_t off = 0;
  auto alloc = [&](size_t bytes) -> void* { void* r = base + off; off += al(bytes); return r; };
  u16*   hres = (u16*)  alloc(NE * 1024);
  u16*   tres = (u16*)  alloc(ND * 1024);
  float* cb   = (float*)alloc(ND * 64);
  float* sg   = (float*)alloc(ND * 4);
  u16*   bigc = (u16*)  alloc((size_t)G * 5376 * 2048 * 2);
  u16*   aobc = (u16*)  alloc((size_t)G * 5376 * 512 * 2);
  u16*   wbuf = (u16*)  alloc((size_t)G * 2048 * 512 * 2);
  u16*   memb = (u16*)  alloc((size_t)G * 1536 * 512 * 2);

  embed_enc_k<<<dim3(37632), 128, 0, stream>>>(batch_x, batch_x_mark, w_in, b_in, hres);
  embed_dec_k<<<dim3(10752), 128, 0, stream>>>(batch_y_mark, w_co, b_co, tres);

  auto cvtw = [&](const float* src, long n_per_f, long f_stride, int g) {
    cvt_w_kernel<<<dim3(512), 256, 0, stream>>>(src, wbuf, n_per_f, f_stride,
                                                (long)g * n_per_f / 4);
  };
  auto gemm = [&](const u16* A, long sAz, u16* C, long sCz, const float* bias, long sBias,
                  int M, int N, int K, int g, int relu) {
    dim3 gr(M / 256, N / 256, g);
    gemm_bf16<<<gr, 512, 0, stream>>>(A, wbuf, C, bias, M, N, K, sAz, (long)N * K, sCz,
                                      sBias, relu);
  };
  auto gemmv = [&](const u16* A, long sAz, u16* C, long sCz, const float* bias, long sBias,
                   int M, int N, int K, int g, int relu) {
    dim3 gr(M / 128, N / 256, g);
    gemm_bf16_v<<<gr, 256, 0, stream>>>(A, wbuf, C, bias, M, N, K, sAz, (long)N * K, sCz,
                                        sBias, relu);
  };

  for (int f0 = 0; f0 < 7; f0 += G) {
    int g = (7 - f0 < G) ? (7 - f0) : G;
    u16* hc = hres + (size_t)f0 * 5376 * 512;
    u16* tc = tres + (size_t)f0 * 1536 * 512;

    // ---------------- encoder (EL = 2) ----------------
    for (int l = 0; l < 2; ++l) {
      cvtw(eqw + (size_t)f0 * 1572864 + (size_t)l * 786432, 786432L, 1572864L, g);
      gemm(hc, 5376L * 512, bigc, 5376L * 1536, eqb + f0 * 3072 + l * 1536, 3072,
           5376, 1536, 512, g, 0);
      attn_mfma<336, 112, 3><<<dim3(8, g * 16, 2), 256, 0, stream>>>(
          bigc, bigc + 512, bigc + 1024, aobc, 336, 1536, 1536, 0, 11);
      cvtw(eow + (size_t)f0 * 524288 + (size_t)l * 262144, 262144L, 524288L, g);
      gemmv(aobc, 5376L * 512, bigc, 5376L * 512, eob + f0 * 1024 + l * 512, 1024,
            5376, 512, 512, g, 0);
      ln_kernel<<<dim3(g * 5376), 128, 0, stream>>>(
          hc, bigc, el1w + f0 * 1024 + l * 512, el1b + f0 * 1024 + l * 512, 5376, 1024);
      cvtw(ef1w + (size_t)f0 * 2097152 + (size_t)l * 1048576, 1048576L, 2097152L, g);
      gemm(hc, 5376L * 512, bigc, 5376L * 2048, ef1b + f0 * 4096 + l * 2048, 4096,
           5376, 2048, 512, g, 1);
      cvtw(ef2w + (size_t)f0 * 2097152 + (size_t)l * 1048576, 1048576L, 2097152L, g);
      gemmv(bigc, 5376L * 2048, aobc, 5376L * 512, ef2b + f0 * 1024 + l * 512, 1024,
            5376, 512, 2048, g, 0);
      ln_kernel<<<dim3(g * 5376), 128, 0, stream>>>(
          hc, aobc, el2w + f0 * 1024 + l * 512, el2b + f0 * 1024 + l * 512, 5376, 1024);
    }

    mem_kernel<<<dim3(g * 16, 6), 256, 0, stream>>>(
        hc, elw + (size_t)f0 * 32256, elb + f0 * 96, memb);

    // ---------------- decoder (DL = 1) ----------------
    cvtw(dsqw + (size_t)f0 * 786432, 786432L, 786432L, g);
    gemmv(tc, 1536L * 512, bigc, 1536L * 1536, dsqb + f0 * 1536, 1536,
          1536, 1536, 512, g, 0);
    attn_mfma<96, 96, 2><<<dim3(8, g * 16, 1), 256, 0, stream>>>(
        bigc, bigc + 512, bigc + 1024, aobc, 96, 1536, 1536, 1, 6);
    cvtw(dsow + (size_t)f0 * 262144, 262144L, 262144L, g);
    gemmv(aobc, 1536L * 512, bigc, 1536L * 512, dsob + f0 * 512, 512,
          1536, 512, 512, g, 0);
    ln_kernel<<<dim3(g * 1536), 128, 0, stream>>>(
        tc, bigc, dl1w + f0 * 512, dl1b + f0 * 512, 1536, 512);

    cvtw(dcqw + (size_t)f0 * 786432, 262144L, 786432L, g);  // Wq rows 0..511
    gemmv(tc, 1536L * 512, bigc, 1536L * 512, dcqb + f0 * 1536, 1536,
          1536, 512, 512, g, 0);
    u16* bigKV = bigc + (size_t)g * 1536 * 512;
    cvtw(dcqw + (size_t)f0 * 786432 + 262144, 524288L, 786432L, g);  // Wk,Wv
    gemmv(memb, 1536L * 512, bigKV, 1536L * 1024, dcqb + f0 * 1536 + 512, 1536,
          1536, 1024, 512, g, 0);
    attn_mfma<96, 96, 2><<<dim3(8, g * 16, 1), 256, 0, stream>>>(
        bigc, bigKV, bigKV + 512, aobc, 96, 512, 1024, 0, 6);
    cvtw(dcow + (size_t)f0 * 262144, 262144L, 262144L, g);
    gemmv(aobc, 1536L * 512, bigc, 1536L * 512, dcob + f0 * 512, 512,
          1536, 512, 512, g, 0);
    ln_kernel<<<dim3(g * 1536), 128, 0, stream>>>(
        tc, bigc, dl2w + f0 * 512, dl2b + f0 * 512, 1536, 512);

    cvtw(df1w + (size_t)f0 * 1048576, 1048576L, 1048576L, g);
    gemmv(tc, 1536L * 512, bigc, 1536L * 2048, df1b + f0 * 2048, 2048,
          1536, 2048, 512, g, 1);
    cvtw(df2w + (size_t)f0 * 1048576, 1048576L, 1048576L, g);
    gemmv(bigc, 1536L * 2048, aobc, 1536L * 512, df2b + f0 * 512, 512,
          1536, 512, 2048, g, 0);
    ln_kernel<<<dim3(g * 1536), 128, 0, stream>>>(
        tc, aobc, dl3w + f0 * 512, dl3b + f0 * 512, 1536, 512);

    head_kernel<<<dim3(g * 1536), 64, 0, stream>>>(tc, wc, bc, wsg, bsg, cb, sg, f0);
  }

  scan_kernel<<<dim3(7), 256, 0, stream>>>(cb, sg, (float*)d_out);
}

// Round 10
// 1468.352 us; speedup vs baseline: 5.2231x; 1.0521x over previous
//
#include <hip/hip_runtime.h>

typedef unsigned short u16;
typedef unsigned int   u32;
typedef __attribute__((ext_vector_type(8))) short short8;
typedef __attribute__((ext_vector_type(4))) float f32x4;

#define DEV static __device__ __forceinline__

DEV float bf2f(u16 u) { return __uint_as_float(((u32)u) << 16); }
DEV u16 f2bf(float f) {
  u32 u = __float_as_uint(f);
  return (u16)((u + 0x7fffu + ((u >> 16) & 1u)) >> 16);
}

#define GLD16(gp, lp) __builtin_amdgcn_global_load_lds( \
    (__attribute__((address_space(1))) u32*)(gp),       \
    (__attribute__((address_space(3))) u32*)(lp), 16, 0, 0)

#define SBAR()  asm volatile("s_barrier" ::: "memory")
#define LGKM0() asm volatile("s_waitcnt lgkmcnt(0)" ::: "memory")

// ---------------------------------------------------------------------------
// Grouped GEMM (round-7 verified): 256x256 tile, BK=64, 8 waves (2Mx4N),
// 4-phase half-tile schedule, counted vmcnt(4), T1/T2/T5, 128KB LDS,
// launch_bounds(512,2) — 112 VGPR + 128 AGPR = 240/wave, 1 block/CU.
// Used for large grids (enc QKV, enc FFN1). M%256==0, N%256==0, K%64, K>=128.
// ---------------------------------------------------------------------------
__global__ __launch_bounds__(512, 2) void gemm_bf16(
    const u16* __restrict__ A, const u16* __restrict__ Bw, u16* __restrict__ C,
    const float* __restrict__ bias, int M, int N, int K,
    long sAz, long sBz, long sCz, long sBiasZ, int relu)
{
  __shared__ __align__(16) u16 Asm[2][2][8192];   // [dbuf][half][128*64]
  __shared__ __align__(16) u16 Bsm[2][2][8192];

  int gx = (int)gridDim.x, gy = (int)gridDim.y;
  int nwg = gx * gy * (int)gridDim.z;
  int orig = (int)blockIdx.x + gx * ((int)blockIdx.y + gy * (int)blockIdx.z);
  int qq = nwg >> 3, rr_ = nwg & 7;
  int xcd = orig & 7, pos = orig >> 3;
  int lg_id = (xcd < rr_) ? (xcd * (qq + 1) + pos) : (rr_ * (qq + 1) + (xcd - rr_) * qq + pos);
  int bz = lg_id / (gx * gy);
  int rem = lg_id - bz * (gx * gy);
  int by = rem / gx, bx = rem - by * gx;

  A += (size_t)bz * sAz; Bw += (size_t)bz * sBz; C += (size_t)bz * sCz; bias += (size_t)bz * sBiasZ;
  int tileM = bx * 256, tileN = by * 256;
  int tid = threadIdx.x, wave = tid >> 6, lane = tid & 63;
  int lr = lane & 15, lgp = lane >> 4;
  int wm = (wave >> 2) * 128;
  int wn = (wave & 3) * 64;
  int ah = wave >> 2;
  int bh = (wave & 3) >> 1;
  int bnb = ((wave & 3) & 1) * 64;

  const int NT = K >> 6;
  const u16* Abase = A + (size_t)tileM * K;
  const u16* Bbase = Bw + (size_t)tileN * K;

  auto SA = [&](int b, int h, int t) {
    const u16* src = Abase + (size_t)h * 128 * K + t * 64;
    #pragma unroll
    for (int i = 0; i < 2; i++) {
      int gi = i * 512 + tid;
      int row = gi >> 3, g = gi & 7;
      GLD16(src + (size_t)row * K + ((g ^ (row & 7)) * 8), Asm[b][h] + (size_t)gi * 8);
    }
  };
  auto SB = [&](int b, int h, int t) {
    const u16* src = Bbase + (size_t)h * 128 * K + t * 64;
    #pragma unroll
    for (int i = 0; i < 2; i++) {
      int gi = i * 512 + tid;
      int row = gi >> 3, g = gi & 7;
      GLD16(src + (size_t)row * K + ((g ^ (row & 7)) * 8), Bsm[b][h] + (size_t)gi * 8);
    }
  };

  f32x4 acc[8][4] = {};

  SA(0, 0, 0); SA(0, 1, 0); SB(0, 0, 0); SB(0, 1, 0);
  if (NT > 1) { SB(1, 0, 1); SB(1, 1, 1); }
  if (NT > 1) asm volatile("s_waitcnt vmcnt(4)" ::: "memory");
  else        asm volatile("s_waitcnt vmcnt(0)" ::: "memory");
  SBAR();

  for (int t = 0; t < NT; ++t) {
    int cur = t & 1;
    const u16* Aslot = Asm[cur][ah];
    const u16* Bslot = Bsm[cur][bh];
    short8 afr[8], b0[4], b1[4];

    // phase 0: read A(m0-3)+B(n0-1); stage A0(t+1)
    #pragma unroll
    for (int mm = 0; mm < 4; ++mm) {
      int rw = mm * 16 + lr;
      #pragma unroll
      for (int ks = 0; ks < 2; ++ks)
        afr[mm * 2 + ks] = *(const short8*)(Aslot + rw * 64 + (((ks * 4 + lgp) ^ (rw & 7)) * 8));
    }
    #pragma unroll
    for (int nn = 0; nn < 2; ++nn) {
      int rw = bnb + nn * 16 + lr;
      #pragma unroll
      for (int ks = 0; ks < 2; ++ks)
        b0[nn * 2 + ks] = *(const short8*)(Bslot + rw * 64 + (((ks * 4 + lgp) ^ (rw & 7)) * 8));
    }
    if (t + 1 < NT) SA(cur ^ 1, 0, t + 1);
    SBAR(); LGKM0();
    __builtin_amdgcn_s_setprio(1);
    #pragma unroll
    for (int mm = 0; mm < 4; ++mm)
      #pragma unroll
      for (int nn = 0; nn < 2; ++nn)
        #pragma unroll
        for (int ks = 0; ks < 2; ++ks)
          acc[mm][nn] = __builtin_amdgcn_mfma_f32_16x16x32_bf16(
              afr[mm * 2 + ks], b0[nn * 2 + ks], acc[mm][nn], 0, 0, 0);
    __builtin_amdgcn_s_setprio(0);
    SBAR();

    // phase 1: read B(n2-3); stage A1(t+1)
    #pragma unroll
    for (int nn = 0; nn < 2; ++nn) {
      int rw = bnb + (nn + 2) * 16 + lr;
      #pragma unroll
      for (int ks = 0; ks < 2; ++ks)
        b1[nn * 2 + ks] = *(const short8*)(Bslot + rw * 64 + (((ks * 4 + lgp) ^ (rw & 7)) * 8));
    }
    if (t + 1 < NT) SA(cur ^ 1, 1, t + 1);
    SBAR(); LGKM0();
    __builtin_amdgcn_s_setprio(1);
    #pragma unroll
    for (int mm = 0; mm < 4; ++mm)
      #pragma unroll
      for (int nn = 0; nn < 2; ++nn)
        #pragma unroll
        for (int ks = 0; ks < 2; ++ks)
          acc[mm][nn + 2] = __builtin_amdgcn_mfma_f32_16x16x32_bf16(
              afr[mm * 2 + ks], b1[nn * 2 + ks], acc[mm][nn + 2], 0, 0, 0);
    __builtin_amdgcn_s_setprio(0);
    SBAR();

    // phase 2: read A(m4-7); stage B0(t+2)
    #pragma unroll
    for (int mm = 0; mm < 4; ++mm) {
      int rw = (mm + 4) * 16 + lr;
      #pragma unroll
      for (int ks = 0; ks < 2; ++ks)
        afr[mm * 2 + ks] = *(const short8*)(Aslot + rw * 64 + (((ks * 4 + lgp) ^ (rw & 7)) * 8));
    }
    if (t + 2 < NT) SB(cur, 0, t + 2);
    SBAR(); LGKM0();
    __builtin_amdgcn_s_setprio(1);
    #pragma unroll
    for (int mm = 0; mm < 4; ++mm)
      #pragma unroll
      for (int nn = 0; nn < 2; ++nn)
        #pragma unroll
        for (int ks = 0; ks < 2; ++ks)
          acc[mm + 4][nn + 2] = __builtin_amdgcn_mfma_f32_16x16x32_bf16(
              afr[mm * 2 + ks], b1[nn * 2 + ks], acc[mm + 4][nn + 2], 0, 0, 0);
    __builtin_amdgcn_s_setprio(0);
    SBAR();

    // phase 3: stage B1(t+2); Q10 (regs only); tile boundary
    if (t + 2 < NT) SB(cur, 1, t + 2);
    __builtin_amdgcn_s_setprio(1);
    #pragma unroll
    for (int mm = 0; mm < 4; ++mm)
      #pragma unroll
      for (int nn = 0; nn < 2; ++nn)
        #pragma unroll
        for (int ks = 0; ks < 2; ++ks)
          acc[mm + 4][nn] = __builtin_amdgcn_mfma_f32_16x16x32_bf16(
              afr[mm * 2 + ks], b0[nn * 2 + ks], acc[mm + 4][nn], 0, 0, 0);
    __builtin_amdgcn_s_setprio(0);
    if (t + 2 < NT) asm volatile("s_waitcnt vmcnt(4)" ::: "memory");
    else            asm volatile("s_waitcnt vmcnt(0)" ::: "memory");
    SBAR();
  }

  float bb[4];
  #pragma unroll
  for (int n = 0; n < 4; ++n) bb[n] = bias[tileN + wn + n * 16 + lr];
  #pragma unroll
  for (int m = 0; m < 8; ++m) {
    #pragma unroll
    for (int rr = 0; rr < 4; ++rr) {
      int mrow = tileM + wm + m * 16 + lgp * 4 + rr;
      u16* crow = C + (size_t)mrow * N + tileN + wn + lr;
      #pragma unroll
      for (int n = 0; n < 4; ++n) {
        float v = acc[m][n][rr] + bb[n];
        if (relu) v = fmaxf(v, 0.f);
        crow[n * 16] = f2bf(v);
      }
    }
  }
}

// ---------------------------------------------------------------------------
// Small-tile GEMM for tail-prone grids: 128x128 tile, 4 waves (2x2, 64x64
// each), BK=32, double-buffered, counted vmcnt(4). LDS 32KB, acc[4][4]=64
// AGPR + ~100 VGPR ≈ 164/wave -> 3 waves/SIMD = 3 blocks/CU (m97/m114
// regime: co-resident waves interleave LDS and MFMA pipes). Same loop
// skeleton + 64B-row XOR swizzle as the round-9 v kernel (refcheck'd,
// 0 bank conflicts). M%128==0, N%128==0, K%32==0, K>=64.
// ---------------------------------------------------------------------------
__global__ __launch_bounds__(256, 2) void gemm_bf16_s(
    const u16* __restrict__ A, const u16* __restrict__ Bw, u16* __restrict__ C,
    const float* __restrict__ bias, int M, int N, int K,
    long sAz, long sBz, long sCz, long sBiasZ, int relu)
{
  __shared__ __align__(16) u16 Asm[2][128 * 32];
  __shared__ __align__(16) u16 Bsm[2][128 * 32];

  int gx = (int)gridDim.x, gy = (int)gridDim.y;
  int nwg = gx * gy * (int)gridDim.z;
  int orig = (int)blockIdx.x + gx * ((int)blockIdx.y + gy * (int)blockIdx.z);
  int qq = nwg >> 3, rr_ = nwg & 7;
  int xcd = orig & 7, pos = orig >> 3;
  int lg_id = (xcd < rr_) ? (xcd * (qq + 1) + pos) : (rr_ * (qq + 1) + (xcd - rr_) * qq + pos);
  int bz = lg_id / (gx * gy);
  int rem = lg_id - bz * (gx * gy);
  int by = rem / gx, bx = rem - by * gx;

  A += (size_t)bz * sAz; Bw += (size_t)bz * sBz; C += (size_t)bz * sCz; bias += (size_t)bz * sBiasZ;
  int tileM = bx * 128, tileN = by * 128;
  int tid = threadIdx.x, lane = tid & 63;
  int wave = tid >> 6;
  int lr = lane & 15, lgp = lane >> 4;
  int wm = (wave >> 1) * 64, wn = (wave & 1) * 64;

  const int NT = K >> 5;
  const u16* Abase = A + (size_t)tileM * K;
  const u16* Bbase = Bw + (size_t)tileN * K;

  // stage tile t: A 8KB (2 issues/thread) + B 8KB (2 issues/thread) = 4 vmcnt
  auto STAGE = [&](int b, int t) {
    int kb = t * 32;
    #pragma unroll
    for (int i = 0; i < 2; i++) {
      int gi = i * 256 + tid;
      int row = gi >> 2, g = gi & 3;
      GLD16(Abase + (size_t)row * K + kb + ((g ^ ((row >> 1) & 3)) * 8),
            Asm[b] + (size_t)gi * 8);
    }
    #pragma unroll
    for (int i = 0; i < 2; i++) {
      int gi = i * 256 + tid;
      int row = gi >> 2, g = gi & 3;
      GLD16(Bbase + (size_t)row * K + kb + ((g ^ ((row >> 1) & 3)) * 8),
            Bsm[b] + (size_t)gi * 8);
    }
  };

  f32x4 acc[4][4] = {};

  STAGE(0, 0);
  if (NT > 1) STAGE(1, 1);

  for (int t = 0; t < NT; ++t) {
    int cur = t & 1;
    if (t + 1 < NT) asm volatile("s_waitcnt vmcnt(4)" ::: "memory");
    else            asm volatile("s_waitcnt vmcnt(0)" ::: "memory");
    SBAR();

    const u16* Ab = Asm[cur];
    const u16* Bb = Bsm[cur];
    short8 afr[4], bfr[4];
    #pragma unroll
    for (int m = 0; m < 4; ++m) {
      int rw = wm + m * 16 + lr;
      afr[m] = *(const short8*)(Ab + rw * 32 + ((lgp ^ ((rw >> 1) & 3)) * 8));
    }
    #pragma unroll
    for (int n = 0; n < 4; ++n) {
      int rw = wn + n * 16 + lr;
      bfr[n] = *(const short8*)(Bb + rw * 32 + ((lgp ^ ((rw >> 1) & 3)) * 8));
    }
    __builtin_amdgcn_s_setprio(1);
    #pragma unroll
    for (int m = 0; m < 4; ++m)
      #pragma unroll
      for (int n = 0; n < 4; ++n)
        acc[m][n] = __builtin_amdgcn_mfma_f32_16x16x32_bf16(
            afr[m], bfr[n], acc[m][n], 0, 0, 0);
    __builtin_amdgcn_s_setprio(0);
    LGKM0();
    SBAR();
    if (t + 2 < NT) STAGE(cur, t + 2);
  }

  float bb[4];
  #pragma unroll
  for (int n = 0; n < 4; ++n) bb[n] = bias[tileN + wn + n * 16 + lr];
  #pragma unroll
  for (int m = 0; m < 4; ++m) {
    #pragma unroll
    for (int rr = 0; rr < 4; ++rr) {
      int mrow = tileM + wm + m * 16 + lgp * 4 + rr;
      u16* crow = C + (size_t)mrow * N + tileN + wn + lr;
      #pragma unroll
      for (int n = 0; n < 4; ++n) {
        float v = acc[m][n][rr] + bb[n];
        if (relu) v = fmaxf(v, 0.f);
        crow[n * 16] = f2bf(v);
      }
    }
  }
}

// ---------------------------------------------------------------------------
// fp32 -> bf16 weight slice conversion
// ---------------------------------------------------------------------------
__global__ void cvt_w_kernel(const float* __restrict__ src, u16* __restrict__ dst,
                             long n_per_f, long f_stride, long total4)
{
  long i = (long)blockIdx.x * blockDim.x + threadIdx.x;
  long step = (long)gridDim.x * blockDim.x;
  for (; i < total4; i += step) {
    long e = i * 4;
    long f = e / n_per_f; long r = e - f * n_per_f;
    float4 v = *(const float4*)(src + f * f_stride + r);
    *(ushort4*)(dst + e) = make_ushort4(f2bf(v.x), f2bf(v.y), f2bf(v.z), f2bf(v.w));
  }
}

// ---------------------------------------------------------------------------
// Embeddings (unchanged)
// ---------------------------------------------------------------------------
__global__ __launch_bounds__(128) void embed_enc_k(
    const float* __restrict__ x, const float* __restrict__ mark,
    const float* __restrict__ w_in, const float* __restrict__ b_in,
    u16* __restrict__ hb)
{
  int row = blockIdx.x;
  int f = row / 5376; int rem = row - f * 5376; int b = rem / 336; int s = rem - b * 336;
  int bsix = b * 336 + s;
  float v0 = x[(size_t)bsix * 7 + f];
  float m0 = mark[(size_t)bsix * 4 + 0], m1 = mark[(size_t)bsix * 4 + 1];
  float m2 = mark[(size_t)bsix * 4 + 2], m3 = mark[(size_t)bsix * 4 + 3];
  int d0 = threadIdx.x * 4;
  u16 ob[4];
  #pragma unroll
  for (int c = 0; c < 4; c++) {
    int d = d0 + c;
    const float* w = w_in + d * 5;
    float val = w[0] * v0 + w[1] * m0 + w[2] * m1 + w[3] * m2 + w[4] * m3 + b_in[d];
    int i = d >> 1;
    float dv = expf((float)i * -0.0359778920778f);
    float arg = (float)s * dv;
    val += (d & 1) ? cosf(arg) : sinf(arg);
    ob[c] = f2bf(val);
  }
  *(ushort4*)(hb + (size_t)row * 512 + d0) = make_ushort4(ob[0], ob[1], ob[2], ob[3]);
}

__global__ __launch_bounds__(128) void embed_dec_k(
    const float* __restrict__ ymark, const float* __restrict__ w_co,
    const float* __restrict__ b_co, u16* __restrict__ tb)
{
  int row = blockIdx.x;
  int f = row / 1536; int rem = row - f * 1536; int b = rem / 96; int pp = rem - b * 96;
  int bp = b * 96 + pp;
  float m0 = ymark[(size_t)bp * 4 + 0], m1 = ymark[(size_t)bp * 4 + 1];
  float m2 = ymark[(size_t)bp * 4 + 2], m3 = ymark[(size_t)bp * 4 + 3];
  int d0 = threadIdx.x * 4;
  u16 ob[4];
  #pragma unroll
  for (int c = 0; c < 4; c++) {
    int d = d0 + c;
    const float* w = w_co + d * 4;
    float val = w[0] * m0 + w[1] * m1 + w[2] * m2 + w[3] * m3 + b_co[d];
    int i = d >> 1;
    float dv = expf((float)i * -0.0359778920778f);
    float arg = (float)pp * dv;
    val += (d & 1) ? cosf(arg) : sinf(arg);
    ob[c] = f2bf(val);
  }
  *(ushort4*)(tb + (size_t)row * 512 + d0) = make_ushort4(ob[0], ob[1], ob[2], ob[3]);
}

// ---------------------------------------------------------------------------
// MFMA attention (unchanged — passing)
// ---------------------------------------------------------------------------
template<int LK, int CHUNK, int NQI>
__global__ __launch_bounds__(256) void attn_mfma(
    const u16* __restrict__ q, const u16* __restrict__ k, const u16* __restrict__ v,
    u16* __restrict__ out, int Lq, int qstride, int kvstride, int causal, int qspan)
{
  constexpr int NCH = LK / CHUNK;
  constexpr int NKT = CHUNK / 16;
  constexpr int NKS = (CHUNK + 31) / 32;
  constexpr int KPAD = NKS * 32;
  constexpr int VSTR = KPAD + 8;
  constexpr int NGRP = CHUNK * 8 / 64;

  __shared__ __align__(16) u16 KsS[CHUNK * 64];
  __shared__ __align__(16) u16 VtS[64 * VSTR];
  __shared__ __align__(16) u16 PWS[4][16 * VSTR];

  int hh = blockIdx.x, fb = blockIdx.y;
  int tid = threadIdx.x, wave = tid >> 6, lane = tid & 63;
  int lr = lane & 15, lg = lane >> 4;

  const int nqt = Lq / 16;
  const int qlo = (int)blockIdx.z * qspan;
  const int qhi = (qlo + qspan < nqt) ? (qlo + qspan) : nqt;

  const u16* qp = q + (size_t)fb * Lq * qstride + hh * 64;
  const u16* kp = k + (size_t)fb * LK * kvstride + hh * 64;
  const u16* vp = v + (size_t)fb * LK * kvstride + hh * 64;

  if constexpr (KPAD > CHUNK) {
    constexpr int TW = KPAD - CHUNK;
    for (int i = tid; i < 64 * TW; i += 256)
      VtS[(i / TW) * VSTR + CHUNK + (i % TW)] = 0;
    u16* PW = PWS[wave];
    for (int i = lane; i < 16 * TW; i += 64)
      PW[(i / TW) * VSTR + CHUNK + (i % TW)] = 0;
  }

  f32x4 oacc[NQI][4] = {};
  f32x4 lsum[NQI] = {};
  u16* PW = PWS[wave];

  for (int c = 0; c < NCH; ++c) {
    __syncthreads();

    const u16* kcp = kp + (size_t)c * CHUNK * kvstride;
    for (int grp = wave; grp < NGRP; grp += 4) {
      int gi = grp * 64 + lane;
      int row = gi >> 3, g = gi & 7;
      GLD16(kcp + (size_t)row * kvstride + ((g ^ (row & 7)) * 8), KsS + (size_t)gi * 8);
    }
    const u16* vcp = vp + (size_t)c * CHUNK * kvstride;
    for (int idx = tid; idx < CHUNK * 8; idx += 256) {
      int kk = idx >> 3, dg = idx & 7;
      uint4 pv = *(const uint4*)(vcp + (size_t)kk * kvstride + dg * 8);
      u16* col = VtS + (size_t)(dg * 8) * VSTR + kk;
      col[0 * VSTR] = (u16)pv.x; col[1 * VSTR] = (u16)(pv.x >> 16);
      col[2 * VSTR] = (u16)pv.y; col[3 * VSTR] = (u16)(pv.y >> 16);
      col[4 * VSTR] = (u16)pv.z; col[5 * VSTR] = (u16)(pv.z >> 16);
      col[6 * VSTR] = (u16)pv.w; col[7 * VSTR] = (u16)(pv.w >> 16);
    }
    __syncthreads();

    #pragma unroll
    for (int qi = 0; qi < NQI; ++qi) {
      int qt = qlo + wave + qi * 4;
      if (qt < qhi) {
        const u16* qrow = qp + (size_t)(qt * 16 + lr) * qstride + lg * 8;
        short8 qf0 = *(const short8*)(qrow);
        short8 qf1 = *(const short8*)(qrow + 32);

        f32x4 sacc[NKT];
        #pragma unroll
        for (int t = 0; t < NKT; t++) {
          int row = t * 16 + lr;
          const u16* kb = KsS + row * 64;
          short8 kf0 = *(const short8*)(kb + ((lg ^ (row & 7)) * 8));
          short8 kf1 = *(const short8*)(kb + (((lg + 4) ^ (row & 7)) * 8));
          f32x4 s = {0.f, 0.f, 0.f, 0.f};
          s = __builtin_amdgcn_mfma_f32_16x16x32_bf16(qf0, kf0, s, 0, 0, 0);
          s = __builtin_amdgcn_mfma_f32_16x16x32_bf16(qf1, kf1, s, 0, 0, 0);
          sacc[t] = s;
        }

        #pragma unroll
        for (int t = 0; t < NKT; t++) {
          int kg = c * CHUNK + t * 16 + lr;
          #pragma unroll
          for (int r = 0; r < 4; r++) {
            int qg = qt * 16 + lg * 4 + r;
            float p = (causal && kg > qg) ? 0.f : __expf(sacc[t][r] * 0.125f);
            sacc[t][r] = p;
            lsum[qi][r] += p;
          }
          u16* pw = PW + (size_t)(lg * 4) * VSTR + t * 16 + lr;
          pw[0 * VSTR] = f2bf(sacc[t][0]);
          pw[1 * VSTR] = f2bf(sacc[t][1]);
          pw[2 * VSTR] = f2bf(sacc[t][2]);
          pw[3 * VSTR] = f2bf(sacc[t][3]);
        }

        #pragma unroll
        for (int s = 0; s < NKS; s++) {
          short8 pf = *(const short8*)(PW + (size_t)lr * VSTR + s * 32 + lg * 8);
          #pragma unroll
          for (int j = 0; j < 4; j++) {
            short8 vf = *(const short8*)(VtS + (size_t)(j * 16 + lr) * VSTR + s * 32 + lg * 8);
            oacc[qi][j] = __builtin_amdgcn_mfma_f32_16x16x32_bf16(pf, vf, oacc[qi][j], 0, 0, 0);
          }
        }
      }
    }
  }

  #pragma unroll
  for (int qi = 0; qi < NQI; ++qi) {
    int qt = qlo + wave + qi * 4;
    if (qt < qhi) {
      float l0 = lsum[qi][0], l1 = lsum[qi][1], l2 = lsum[qi][2], l3 = lsum[qi][3];
      #pragma unroll
      for (int m = 1; m < 16; m <<= 1) {
        l0 += __shfl_xor(l0, m);
        l1 += __shfl_xor(l1, m);
        l2 += __shfl_xor(l2, m);
        l3 += __shfl_xor(l3, m);
      }
      float inv[4] = {1.f / l0, 1.f / l1, 1.f / l2, 1.f / l3};
      #pragma unroll
      for (int r = 0; r < 4; r++) {
        size_t orow = (size_t)fb * Lq + qt * 16 + lg * 4 + r;
        u16* ob = out + orow * 512 + hh * 64 + lr;
        #pragma unroll
        for (int j = 0; j < 4; j++)
          ob[j * 16] = f2bf(oacc[qi][j][r] * inv[r]);
      }
    }
  }
}

// ---------------------------------------------------------------------------
// Residual add + LayerNorm (unchanged)
// ---------------------------------------------------------------------------
__global__ __launch_bounds__(128) void ln_kernel(
    u16* __restrict__ h, const u16* __restrict__ delta,
    const float* __restrict__ gamma, const float* __restrict__ beta,
    int rows_per_f, long gstride)
{
  __shared__ float red[2];
  int row = blockIdx.x;
  int f = row / rows_per_f;
  const float* g = gamma + (size_t)f * gstride;
  const float* be = beta + (size_t)f * gstride;
  int d0 = threadIdx.x * 4;
  size_t p = (size_t)row * 512 + d0;
  ushort4 hv = *(const ushort4*)(h + p);
  ushort4 dv = *(const ushort4*)(delta + p);
  float x0 = bf2f(hv.x) + bf2f(dv.x), x1 = bf2f(hv.y) + bf2f(dv.y);
  float x2 = bf2f(hv.z) + bf2f(dv.z), x3 = bf2f(hv.w) + bf2f(dv.w);
  float ssum = x0 + x1 + x2 + x3;
  #pragma unroll
  for (int m = 1; m < 64; m <<= 1) ssum += __shfl_xor(ssum, m);
  if ((threadIdx.x & 63) == 0) red[threadIdx.x >> 6] = ssum;
  __syncthreads();
  float mean = (red[0] + red[1]) * (1.f / 512.f);
  __syncthreads();
  float c0 = x0 - mean, c1 = x1 - mean, c2 = x2 - mean, c3 = x3 - mean;
  float sq = c0 * c0 + c1 * c1 + c2 * c2 + c3 * c3;
  #pragma unroll
  for (int m = 1; m < 64; m <<= 1) sq += __shfl_xor(sq, m);
  if ((threadIdx.x & 63) == 0) red[threadIdx.x >> 6] = sq;
  __syncthreads();
  float var = (red[0] + red[1]) * (1.f / 512.f);
  float rstd = rsqrtf(var + 1e-5f);
  float y0 = c0 * rstd * g[d0 + 0] + be[d0 + 0];
  float y1 = c1 * rstd * g[d0 + 1] + be[d0 + 1];
  float y2 = c2 * rstd * g[d0 + 2] + be[d0 + 2];
  float y3 = c3 * rstd * g[d0 + 3] + be[d0 + 3];
  *(ushort4*)(h + p) = make_ushort4(f2bf(y0), f2bf(y1), f2bf(y2), f2bf(y3));
}

// ---------------------------------------------------------------------------
// mem projection (unchanged)
// ---------------------------------------------------------------------------
__global__ __launch_bounds__(256) void mem_kernel(
    const u16* __restrict__ h, const float* __restrict__ elw,
    const float* __restrict__ elb, u16* __restrict__ memb)
{
  int fb = blockIdx.x; int f = fb >> 4;
  int pc = blockIdx.y;
  int d0 = threadIdx.x * 2;
  const u16* hbase = h + (size_t)fb * 336 * 512;
  const float* wbase = elw + (size_t)f * 96 * 336 + (size_t)pc * 16 * 336;
  float a0[16], a1[16];
  #pragma unroll
  for (int pp = 0; pp < 16; pp++) { a0[pp] = 0.f; a1[pp] = 0.f; }
  for (int s = 0; s < 336; s++) {
    ushort2 h2 = *(const ushort2*)(hbase + (size_t)s * 512 + d0);
    float hx = bf2f(h2.x), hy = bf2f(h2.y);
    #pragma unroll
    for (int pp = 0; pp < 16; pp++) {
      float w = wbase[pp * 336 + s];
      a0[pp] += w * hx; a1[pp] += w * hy;
    }
  }
  #pragma unroll
  for (int pp = 0; pp < 16; pp++) {
    int pidx = pc * 16 + pp;
    size_t row = (size_t)fb * 96 + pidx;
    float e = elb[f * 96 + pidx];
    *(ushort2*)(memb + row * 512 + d0) = make_ushort2(f2bf(a0[pp] + e), f2bf(a1[pp] + e));
  }
}

// ---------------------------------------------------------------------------
// Output head (unchanged)
// ---------------------------------------------------------------------------
__global__ __launch_bounds__(64) void head_kernel(
    const u16* __restrict__ td, const float* __restrict__ wcp, const float* __restrict__ bcp,
    const float* __restrict__ wsp, const float* __restrict__ bsp,
    float* __restrict__ cb, float* __restrict__ sg, int f0)
{
  int rl = blockIdx.x, lane = threadIdx.x;
  size_t row = (size_t)f0 * 1536 + rl;
  const u16* x = td + (size_t)rl * 512;
  float xr[8];
  #pragma unroll
  for (int j = 0; j < 8; j++) xr[j] = bf2f(x[lane + 64 * j]);
  #pragma unroll
  for (int o = 0; o < 16; o++) {
    const float* w = wcp + o * 512;
    float p = 0.f;
    #pragma unroll
    for (int j = 0; j < 8; j++) p += xr[j] * w[lane + 64 * j];
    #pragma unroll
    for (int m = 1; m < 64; m <<= 1) p += __shfl_xor(p, m);
    if (lane == 0) {
      float cv = (p + bcp[o]) / 6.0f + 0.5f;
      cb[row * 16 + o] = fminf(fmaxf(cv, 0.f), 1.f);
    }
  }
  float p = 0.f;
  #pragma unroll
  for (int j = 0; j < 8; j++) p += xr[j] * wsp[lane + 64 * j];
  #pragma unroll
  for (int m = 1; m < 64; m <<= 1) p += __shfl_xor(p, m);
  if (lane == 0) {
    float zv = p + bsp[0];
    sg[row] = (zv > 20.f) ? zv : log1pf(expf(zv));
  }
}

// ---------------------------------------------------------------------------
// TAO scan (unchanged)
// ---------------------------------------------------------------------------
__global__ __launch_bounds__(256) void scan_kernel(
    const float* __restrict__ cbuf, const float* __restrict__ sgb, float* __restrict__ outp)
{
  int f = blockIdx.x;
  int b = threadIdx.x >> 4;
  int s = threadIdx.x & 15;
  size_t rbase = ((size_t)f * 16 + b) * 96;
  float a = cbuf[rbase * 16 + s];
  for (int p = 0; p < 96; ++p) {
    float cd = cbuf[(rbase + p) * 16 + s];
    float sd = sgb[rbase + p];
    float xs = (s >= 1 && s <= 14) ? a : 0.f;
    #pragma unroll
    for (int m = 1; m < 16; m <<= 1) xs += __shfl_xor(xs, m);
    float up = __shfl_up(a, 1, 16);
    float an = (s == 0) ? (a + cd) : ((s == 1) ? (cd - xs) : (up + cd));
    a = an;
    float y01 = __shfl(a, 0, 16) + __shfl(a, 1, 16) + sd;
    if (s == 0) outp[((size_t)b * 96 + p) * 7 + f] = y01;
  }
}

__global__ void diag_kernel(float* __restrict__ out, float v, int n)
{
  int i = blockIdx.x * 256 + threadIdx.x;
  if (i < n) out[i] = v;
}

// ---------------------------------------------------------------------------
extern "C" void kernel_launch(void* const* d_in, const int* in_sizes, int n_in,
                              void* d_out, int out_size, void* d_ws, size_t ws_size,
                              hipStream_t stream)
{
  (void)in_sizes; (void)n_in;
  const float* batch_x      = (const float*)d_in[0];
  const float* batch_x_mark = (const float*)d_in[1];
  const float* batch_y_mark = (const float*)d_in[3];
  const float* w_in = (const float*)d_in[4];
  const float* b_in = (const float*)d_in[5];
  const float* w_co = (const float*)d_in[6];
  const float* b_co = (const float*)d_in[7];
  const float* eqw  = (const float*)d_in[8];
  const float* eqb  = (const float*)d_in[9];
  const float* eow  = (const float*)d_in[10];
  const float* eob  = (const float*)d_in[11];
  const float* el1w = (const float*)d_in[12];
  const float* el1b = (const float*)d_in[13];
  const float* el2w = (const float*)d_in[14];
  const float* el2b = (const float*)d_in[15];
  const float* ef1w = (const float*)d_in[16];
  const float* ef1b = (const float*)d_in[17];
  const float* ef2w = (const float*)d_in[18];
  const float* ef2b = (const float*)d_in[19];
  const float* elw  = (const float*)d_in[20];
  const float* elb  = (const float*)d_in[21];
  const float* dsqw = (const float*)d_in[22];
  const float* dsqb = (const float*)d_in[23];
  const float* dsow = (const float*)d_in[24];
  const float* dsob = (const float*)d_in[25];
  const float* dcqw = (const float*)d_in[26];
  const float* dcqb = (const float*)d_in[27];
  const float* dcow = (const float*)d_in[28];
  const float* dcob = (const float*)d_in[29];
  const float* dl1w = (const float*)d_in[30];
  const float* dl1b = (const float*)d_in[31];
  const float* dl2w = (const float*)d_in[32];
  const float* dl2b = (const float*)d_in[33];
  const float* dl3w = (const float*)d_in[34];
  const float* dl3b = (const float*)d_in[35];
  const float* df1w = (const float*)d_in[36];
  const float* df1b = (const float*)d_in[37];
  const float* df2w = (const float*)d_in[38];
  const float* df2b = (const float*)d_in[39];
  const float* wc   = (const float*)d_in[40];
  const float* bc   = (const float*)d_in[41];
  const float* wsg  = (const float*)d_in[42];
  const float* bsg  = (const float*)d_in[43];

  const size_t NE = 37632;   // F*B*SEQ
  const size_t ND = 10752;   // F*B*PRED
  auto al = [](size_t x) { return (x + 255) & ~(size_t)255; };

  size_t fixedB = al(NE * 1024) + al(ND * 1024) + al(ND * 64) + al(ND * 4);
  int G = 0;
  for (int g = 7; g >= 1; --g) {
    size_t need = fixedB
        + al((size_t)g * 5376 * 2048 * 2)
        + al((size_t)g * 5376 * 512 * 2)
        + al((size_t)g * 2048 * 512 * 2)
        + al((size_t)g * 1536 * 512 * 2);
    if (need <= ws_size) { G = g; break; }
  }
  if (G == 0) {
    diag_kernel<<<dim3((out_size + 255) / 256), 256, 0, stream>>>(
        (float*)d_out, 1000.0f + (float)(ws_size >> 20), out_size);
    return;
  }

  char* base = (char*)d_ws;
  size_t off = 0;
  auto alloc = [&](size_t bytes) -> void* { void* r = base + off; off += al(bytes); return r; };
  u16*   hres = (u16*)  alloc(NE * 1024);
  u16*   tres = (u16*)  alloc(ND * 1024);
  float* cb   = (float*)alloc(ND * 64);
  float* sg   = (float*)alloc(ND * 4);
  u16*   bigc = (u16*)  alloc((size_t)G * 5376 * 2048 * 2);
  u16*   aobc = (u16*)  alloc((size_t)G * 5376 * 512 * 2);
  u16*   wbuf = (u16*)  alloc((size_t)G * 2048 * 512 * 2);
  u16*   memb = (u16*)  alloc((size_t)G * 1536 * 512 * 2);

  embed_enc_k<<<dim3(37632), 128, 0, stream>>>(batch_x, batch_x_mark, w_in, b_in, hres);
  embed_dec_k<<<dim3(10752), 128, 0, stream>>>(batch_y_mark, w_co, b_co, tres);

  auto cvtw = [&](const float* src, long n_per_f, long f_stride, int g) {
    cvt_w_kernel<<<dim3(512), 256, 0, stream>>>(src, wbuf, n_per_f, f_stride,
                                                (long)g * n_per_f / 4);
  };
  auto gemm = [&](const u16* A, long sAz, u16* C, long sCz, const float* bias, long sBias,
                  int M, int N, int K, int g, int relu) {
    dim3 gr(M / 256, N / 256, g);
    gemm_bf16<<<gr, 512, 0, stream>>>(A, wbuf, C, bias, M, N, K, sAz, (long)N * K, sCz,
                                      sBias, relu);
  };
  auto gemms = [&](const u16* A, long sAz, u16* C, long sCz, const float* bias, long sBias,
                   int M, int N, int K, int g, int relu) {
    dim3 gr(M / 128, N / 128, g);
    gemm_bf16_s<<<gr, 256, 0, stream>>>(A, wbuf, C, bias, M, N, K, sAz, (long)N * K, sCz,
                                        sBias, relu);
  };

  for (int f0 = 0; f0 < 7; f0 += G) {
    int g = (7 - f0 < G) ? (7 - f0) : G;
    u16* hc = hres + (size_t)f0 * 5376 * 512;
    u16* tc = tres + (size_t)f0 * 1536 * 512;

    // ---------------- encoder (EL = 2) ----------------
    for (int l = 0; l < 2; ++l) {
      cvtw(eqw + (size_t)f0 * 1572864 + (size_t)l * 786432, 786432L, 1572864L, g);
      gemm(hc, 5376L * 512, bigc, 5376L * 1536, eqb + f0 * 3072 + l * 1536, 3072,
           5376, 1536, 512, g, 0);
      attn_mfma<336, 112, 3><<<dim3(8, g * 16, 2), 256, 0, stream>>>(
          bigc, bigc + 512, bigc + 1024, aobc, 336, 1536, 1536, 0, 11);
      cvtw(eow + (size_t)f0 * 524288 + (size_t)l * 262144, 262144L, 524288L, g);
      gemms(aobc, 5376L * 512, bigc, 5376L * 512, eob + f0 * 1024 + l * 512, 1024,
            5376, 512, 512, g, 0);
      ln_kernel<<<dim3(g * 5376), 128, 0, stream>>>(
          hc, bigc, el1w + f0 * 1024 + l * 512, el1b + f0 * 1024 + l * 512, 5376, 1024);
      cvtw(ef1w + (size_t)f0 * 2097152 + (size_t)l * 1048576, 1048576L, 2097152L, g);
      gemm(hc, 5376L * 512, bigc, 5376L * 2048, ef1b + f0 * 4096 + l * 2048, 4096,
           5376, 2048, 512, g, 1);
      cvtw(ef2w + (size_t)f0 * 2097152 + (size_t)l * 1048576, 1048576L, 2097152L, g);
      gemms(bigc, 5376L * 2048, aobc, 5376L * 512, ef2b + f0 * 1024 + l * 512, 1024,
            5376, 512, 2048, g, 0);
      ln_kernel<<<dim3(g * 5376), 128, 0, stream>>>(
          hc, aobc, el2w + f0 * 1024 + l * 512, el2b + f0 * 1024 + l * 512, 5376, 1024);
    }

    mem_kernel<<<dim3(g * 16, 6), 256, 0, stream>>>(
        hc, elw + (size_t)f0 * 32256, elb + f0 * 96, memb);

    // ---------------- decoder (DL = 1) ----------------
    cvtw(dsqw + (size_t)f0 * 786432, 786432L, 786432L, g);
    gemms(tc, 1536L * 512, bigc, 1536L * 1536, dsqb + f0 * 1536, 1536,
          1536, 1536, 512, g, 0);
    attn_mfma<96, 96, 2><<<dim3(8, g * 16, 1), 256, 0, stream>>>(
        bigc, bigc + 512, bigc + 1024, aobc, 96, 1536, 1536, 1, 6);
    cvtw(dsow + (size_t)f0 * 262144, 262144L, 262144L, g);
    gemms(aobc, 1536L * 512, bigc, 1536L * 512, dsob + f0 * 512, 512,
          1536, 512, 512, g, 0);
    ln_kernel<<<dim3(g * 1536), 128, 0, stream>>>(
        tc, bigc, dl1w + f0 * 512, dl1b + f0 * 512, 1536, 512);

    cvtw(dcqw + (size_t)f0 * 786432, 262144L, 786432L, g);  // Wq rows 0..511
    gemms(tc, 1536L * 512, bigc, 1536L * 512, dcqb + f0 * 1536, 1536,
          1536, 512, 512, g, 0);
    u16* bigKV = bigc + (size_t)g * 1536 * 512;
    cvtw(dcqw + (size_t)f0 * 786432 + 262144, 524288L, 786432L, g);  // Wk,Wv
    gemms(memb, 1536L * 512, bigKV, 1536L * 1024, dcqb + f0 * 1536 + 512, 1536,
          1536, 1024, 512, g, 0);
    attn_mfma<96, 96, 2><<<dim3(8, g * 16, 1), 256, 0, stream>>>(
        bigc, bigKV, bigKV + 512, aobc, 96, 512, 1024, 0, 6);
    cvtw(dcow + (size_t)f0 * 262144, 262144L, 262144L, g);
    gemms(aobc, 1536L * 512, bigc, 1536L * 512, dcob + f0 * 512, 512,
          1536, 512, 512, g, 0);
    ln_kernel<<<dim3(g * 1536), 128, 0, stream>>>(
        tc, bigc, dl2w + f0 * 512, dl2b + f0 * 512, 1536, 512);

    cvtw(df1w + (size_t)f0 * 1048576, 1048576L, 1048576L, g);
    gemms(tc, 1536L * 512, bigc, 1536L * 2048, df1b + f0 * 2048, 2048,
          1536, 2048, 512, g, 1);
    cvtw(df2w + (size_t)f0 * 1048576, 1048576L, 1048576L, g);
    gemms(bigc, 1536L * 2048, aobc, 1536L * 512, df2b + f0 * 512, 512,
          1536, 512, 2048, g, 0);
    ln_kernel<<<dim3(g * 1536), 128, 0, stream>>>(
        tc, aobc, dl3w + f0 * 512, dl3b + f0 * 512, 1536, 512);

    head_kernel<<<dim3(g * 1536), 64, 0, stream>>>(tc, wc, bc, wsg, bsg, cb, sg, f0);
  }

  scan_kernel<<<dim3(7), 256, 0, stream>>>(cb, sg, (float*)d_out);
}